// Round 11
// baseline (464.511 us; speedup 1.0000x reference)
//
#include <hip/hip_runtime.h>
#include <hip/hip_bf16.h>

typedef __hip_bfloat16 bf16;
typedef __attribute__((ext_vector_type(8))) short s16x8;
typedef __attribute__((ext_vector_type(4))) float f32x4;

// ---------- helpers ----------
__device__ __forceinline__ float2 bfpair(unsigned u) {
    float2 r;
    r.x = __uint_as_float(u << 16);
    r.y = __uint_as_float(u & 0xffff0000u);
    return r;
}

__device__ __forceinline__ unsigned short f2bf_bits(float f) {
    unsigned u = __float_as_uint(f);
    return (unsigned short)((u + 0x7fffu + ((u >> 16) & 1u)) >> 16);
}

// async global->LDS, 16B per lane; LDS dest wave-uniform base (lane*16 implicit)
typedef const __attribute__((address_space(1))) unsigned GU;
typedef __attribute__((address_space(3))) unsigned LU;
__device__ __forceinline__ void gload_lds16(const void* g, void* l) {
    __builtin_amdgcn_global_load_lds((GU*)g, (LU*)l, 16, 0, 0);
}

// ---------- fused setup: prepw (+bias pack) | zero deg | canon ei | LN1 ----------
// block ranges: [0,770) prepw; [770,+nzero) zero deg; [.., +2000) canon; rest LN1
__global__ __launch_bounds__(256) void setup_k(const float* __restrict__ Wq,
                                               const float* __restrict__ Wk,
                                               const float* __restrict__ Wv,
                                               const float* __restrict__ Wo,
                                               const float* __restrict__ W1,
                                               const float* __restrict__ W2,
                                               const float* __restrict__ bq,
                                               const float* __restrict__ bk,
                                               const float* __restrict__ bv,
                                               unsigned short* __restrict__ qkvH,
                                               unsigned short* __restrict__ qkvL,
                                               unsigned short* __restrict__ woH,
                                               unsigned short* __restrict__ woL,
                                               unsigned short* __restrict__ w1H,
                                               unsigned short* __restrict__ w1L,
                                               unsigned short* __restrict__ w2H,
                                               unsigned short* __restrict__ w2L,
                                               float* __restrict__ bqkv,
                                               int* __restrict__ deg,
                                               const unsigned* __restrict__ eisrc,
                                               int* __restrict__ ei32,
                                               const float* __restrict__ x,
                                               const float* __restrict__ g1,
                                               const float* __restrict__ b1,
                                               bf16* __restrict__ hb,
                                               int N, int twoE, int nzero) {
    int b = blockIdx.x;
    int tid = threadIdx.x;
    if (b < 770) {
        int idx = b * 256 + tid;
        if (idx >= 196608) {
            int i = idx - 196608;
            if (i < 384) bqkv[i] = (i < 128) ? bq[i] : (i < 256) ? bk[i - 128] : bv[i - 256];
            return;
        }
        float w; unsigned short *H, *L; int oi;
        if (idx < 49152) {
            int n = idx >> 7, kx = idx & 127;
            const float* W = (n < 128) ? Wq : (n < 256) ? Wk : Wv;
            w = W[kx * 128 + (n & 127)];
            H = qkvH; L = qkvL; oi = idx;
        } else if (idx < 65536) {
            int li = idx - 49152; int n = li >> 7, kx = li & 127;
            w = Wo[kx * 128 + n]; H = woH; L = woL; oi = li;
        } else if (idx < 131072) {
            int li = idx - 65536; int n = li >> 7, kx = li & 127;
            w = W1[(size_t)kx * 512 + n]; H = w1H; L = w1L; oi = li;
        } else {
            int li = idx - 131072; int n = li >> 9, kx = li & 511;
            w = W2[(size_t)kx * 128 + n]; H = w2H; L = w2L; oi = li;
        }
        unsigned short hbits = f2bf_bits(w);
        float hf = __uint_as_float((unsigned)hbits << 16);
        H[oi] = hbits;
        L[oi] = f2bf_bits(w - hf);
        return;
    }
    if (b < 770 + nzero) {
        int i = (b - 770) * 256 + tid;
        if (i < N) deg[i] = 0;
        return;
    }
    if (b < 770 + nzero + 2000) {
        // canon: detect int64 vs int32 (parallel), convert to int32
        __shared__ int s_nz;
        if (tid == 0) s_nz = 0;
        __syncthreads();
        if (eisrc[2 * tid + 1] != 0u) atomicAdd(&s_nz, 1);
        __syncthreads();
        bool is64 = (s_nz == 0);
        long long i = (long long)(b - 770 - nzero) * 256 + tid;
        long long st = (long long)2000 * 256;
        if (is64) { for (; i < twoE; i += st) ei32[i] = (int)eisrc[2 * i]; }
        else      { for (; i < twoE; i += st) ei32[i] = (int)eisrc[i]; }
        return;
    }
    // LN1: one wave per 128-elem row
    int row = (b - 770 - nzero - 2000) * 4 + (tid >> 6);
    if (row >= N) return;
    int lane = tid & 63;
    float2 f = ((const float2*)x)[(size_t)row * 64 + lane];
    float s = f.x + f.y;
    #pragma unroll
    for (int off = 32; off > 0; off >>= 1) s += __shfl_xor(s, off);
    float mean = s * (1.0f / 128.0f);
    float d0 = f.x - mean, d1 = f.y - mean;
    float vs = d0 * d0 + d1 * d1;
    #pragma unroll
    for (int off = 32; off > 0; off >>= 1) vs += __shfl_xor(vs, off);
    float rstd = rsqrtf(vs * (1.0f / 128.0f) + 1e-5f);
    float2 gg = ((const float2*)g1)[lane];
    float2 bb = ((const float2*)b1)[lane];
    float o0 = d0 * rstd * gg.x + bb.x;
    float o1 = d1 * rstd * gg.y + bb.y;
    unsigned pk = ((unsigned)f2bf_bits(o1) << 16) | (unsigned)f2bf_bits(o0);
    ((unsigned*)hb)[(size_t)row * 64 + lane] = pk;
}

// ---------- CSR build ----------
__global__ __launch_bounds__(256) void count_deg_k(const int* __restrict__ ei,
                                                   int* __restrict__ deg, int E) {
    int e = blockIdx.x * 256 + threadIdx.x;
    if (e < E) atomicAdd(&deg[ei[E + e]], 1);
}

#define SCAN_BLK 1024
__global__ __launch_bounds__(256) void scan1_k(const int* __restrict__ deg,
                                               int* __restrict__ off,
                                               int* __restrict__ bsum, int n) {
    __shared__ int s[256];
    int base = blockIdx.x * SCAN_BLK;
    int t = threadIdx.x;
    int v[4]; int sum = 0;
    #pragma unroll
    for (int j = 0; j < 4; j++) {
        int idx = base + t * 4 + j;
        v[j] = (idx < n) ? deg[idx] : 0;
        sum += v[j];
    }
    s[t] = sum; __syncthreads();
    for (int o = 1; o < 256; o <<= 1) {
        int add = (t >= o) ? s[t - o] : 0;
        __syncthreads();
        s[t] += add;
        __syncthreads();
    }
    int run = (t > 0) ? s[t - 1] : 0;
    if (t == 255) bsum[blockIdx.x] = s[255];
    #pragma unroll
    for (int j = 0; j < 4; j++) {
        int idx = base + t * 4 + j;
        if (idx < n) off[idx] = run;
        run += v[j];
    }
}

// scan3 with scan2 (block-sum exclusive prefix) recomputed inline per block
__global__ __launch_bounds__(256) void scan3_k(int* __restrict__ off,
                                               int* __restrict__ cursor,
                                               const int* __restrict__ bsum,
                                               int n, int nb) {
    __shared__ int sb[64];
    int t = threadIdx.x;
    if (t < 64) {
        int own = (t < nb) ? bsum[t] : 0;
        int v = own;
        #pragma unroll
        for (int o = 1; o < 64; o <<= 1) {
            int u = __shfl_up(v, o);
            if ((t & 63) >= o) v += u;
        }
        sb[t] = v - own;   // exclusive
    }
    __syncthreads();
    int i = blockIdx.x * 256 + t;
    if (i < n) {
        int o = off[i] + sb[i / SCAN_BLK];
        off[i] = o;
        cursor[i] = o;
    }
}

__global__ __launch_bounds__(256) void scatter_k(const int* __restrict__ ei,
                                                 int* __restrict__ cursor,
                                                 int* __restrict__ csr, int E) {
    int e = blockIdx.x * 256 + threadIdx.x;
    if (e >= E) return;
    int s = ei[e], d = ei[E + e];
    int pos = atomicAdd(&cursor[d], 1);
    csr[pos] = s;
}

// ---------- MFMA GEMM: A via double-buffered LDS, B direct global->reg ----------
// C[m,n] = A[m,:] @ (Bh+Bl)[n,:] + bias[n] (+gelu / +res / +fused-LN2-out)
// A: bf16 [Mp][K] row-major. B: bf16 [N][K] (pre-transposed), L2-resident (small).
// 256 thr = 4 waves (2x2); block tile BM x 128; wave tile (BM/2) x 64.
// LDS holds ONLY the A tile (2 x BM x 64B dbuf) -> 16KB @BM=128, 8KB @BM=64:
// occupancy-bound by VGPR (~4-5 blocks/CU) instead of 48KB LDS (R10: 22% occ).
// B fragments (8 x 16B per wave per step) load straight from global: weight
// panels are <=256KB, L2-resident across all row-blocks.
template <int EPI, bool OUTBF, int K, int BM, bool LNF>
__global__ __launch_bounds__(256) void mgemm_k(const bf16* __restrict__ A,
                                               const bf16* __restrict__ Bh,
                                               const bf16* __restrict__ Bl,
                                               const float* __restrict__ bias,
                                               const float* __restrict__ res,
                                               void* __restrict__ outp,
                                               const float* __restrict__ lg,
                                               const float* __restrict__ lb,
                                               bf16* __restrict__ hbout,
                                               long long sub_off, int M,
                                               int ldo, int sub_shift) {
    constexpr int MF = BM / 32;                 // 16-row frags per wave in m
    constexpr int NK = K / 32;                  // K-steps
    constexpr int STEP = BM * 64;               // A tile only: BM rows x 64B
    __shared__ __align__(16) char smem[2 * STEP];

    const int lane = threadIdx.x & 63;
    const int wid  = threadIdx.x >> 6;
    const int wr = wid >> 1, wc = wid & 1;
    const int lrow = lane & 15, lk = lane >> 4;  // lk 0..3 = 16B chunk in 64B row
    const int m0 = blockIdx.y * BM;
    const int mw0 = wr * (BM / 2);
    const int n0 = blockIdx.x * 128 + wc * 64;
    const int srow = lane >> 2;                  // staging: row within 16-row group
    const int schunk = (lane & 3) ^ (srow & 3);  // pre-swizzled source chunk

    const char* Ab  = (const char*)A + (size_t)m0 * (K * 2);
    const bf16* Bhp[4]; const bf16* Blp[4];
    #pragma unroll
    for (int nf = 0; nf < 4; nf++) {
        int rb = n0 + nf * 16 + lrow;
        Bhp[nf] = Bh + (size_t)rb * K + lk * 8;
        Blp[nf] = Bl + (size_t)rb * K + lk * 8;
    }

    f32x4 acc[MF][4];
    #pragma unroll
    for (int mf = 0; mf < MF; mf++)
        #pragma unroll
        for (int nf = 0; nf < 4; nf++) {
            f32x4 z = {0.f, 0.f, 0.f, 0.f};
            acc[mf][nf] = z;
        }

    auto stage = [&](int kt, int bufb) {         // A only
        const int kb = kt * 64;                  // byte offset into K
        char* sb = &smem[bufb];
        #pragma unroll
        for (int it = 0; it < BM / 64; it++) {   // 16 rows per instr
            int rg = wid * (BM / 4) + it * 16;
            gload_lds16(Ab + (size_t)(rg + srow) * (K * 2) + kb + schunk * 16,
                        sb + rg * 64);
        }
    };

    auto compute = [&](int kt, int bufb) {
        const char* sb = &smem[bufb];
        const int ko = kt * 32;                  // element offset into K
        s16x8 bh[4], bl[4];
        #pragma unroll
        for (int nf = 0; nf < 4; nf++) {         // B: global->reg (L2-hit)
            bh[nf] = *(const s16x8*)(Bhp[nf] + ko);
            bl[nf] = *(const s16x8*)(Blp[nf] + ko);
        }
        s16x8 a[MF];
        #pragma unroll
        for (int mf = 0; mf < MF; mf++) {
            int ra = mw0 + mf * 16 + lrow;
            a[mf] = *(const s16x8*)(sb + ra * 64 + ((lk ^ (ra & 3)) * 16));
        }
        #pragma unroll
        for (int mf = 0; mf < MF; mf++)
            #pragma unroll
            for (int nf = 0; nf < 4; nf++)
                acc[mf][nf] = __builtin_amdgcn_mfma_f32_16x16x32_bf16(a[mf], bh[nf], acc[mf][nf], 0, 0, 0);
        #pragma unroll
        for (int mf = 0; mf < MF; mf++)
            #pragma unroll
            for (int nf = 0; nf < 4; nf++)
                acc[mf][nf] = __builtin_amdgcn_mfma_f32_16x16x32_bf16(a[mf], bl[nf], acc[mf][nf], 0, 0, 0);
    };

    stage(0, 0);
    for (int kt = 0; kt < NK; kt++) {
        __syncthreads();                         // buf[kt] staged; WAR-safe for next stage
        if (kt + 1 < NK) stage(kt + 1, ((kt + 1) & 1) * STEP);
        compute(kt, (kt & 1) * STEP);
    }

    if (!LNF) {
        const int nmask = (1 << sub_shift) - 1;
        #pragma unroll
        for (int mf = 0; mf < MF; mf++) {
            #pragma unroll
            for (int nf = 0; nf < 4; nf++) {
                int n = n0 + nf * 16 + lrow;
                float bsv = bias[n];
                #pragma unroll
                for (int r = 0; r < 4; r++) {
                    int m = m0 + mw0 + mf * 16 + lk * 4 + r;
                    if (m >= M) continue;
                    float val = acc[mf][nf][r] + bsv;
                    if (EPI == 1) val = 0.5f * val * (1.0f + erff(val * 0.70710678118f));
                    if (EPI == 2) val += res[(size_t)m * ldo + n];
                    long long oidx = (long long)m * ldo + (n & nmask) + (long long)(n >> sub_shift) * sub_off;
                    if (OUTBF) ((unsigned short*)outp)[oidx] = f2bf_bits(val);
                    else       ((float*)outp)[oidx] = val;
                }
            }
        }
    } else {
        // fused epilogue: out = acc + bias + res (fp32), then LN(out) -> bf16 hbout.
        // BM==64, ldo==128, gx==1: block owns full rows; cross-wave reduce via LDS.
        float vals[MF][4][4];
        float s1[MF][4], s2[MF][4];
        #pragma unroll
        for (int mf = 0; mf < MF; mf++)
            #pragma unroll
            for (int r = 0; r < 4; r++) { s1[mf][r] = 0.f; s2[mf][r] = 0.f; }
        #pragma unroll
        for (int mf = 0; mf < MF; mf++) {
            #pragma unroll
            for (int r = 0; r < 4; r++) {
                int m = m0 + mw0 + mf * 16 + lk * 4 + r;
                #pragma unroll
                for (int nf = 0; nf < 4; nf++) {
                    int n = n0 + nf * 16 + lrow;
                    float val = acc[mf][nf][r] + bias[n];
                    val += (m < M) ? res[(size_t)m * 128 + n] : 0.f;
                    vals[mf][nf][r] = val;
                    s1[mf][r] += val;
                    s2[mf][r] += val * val;
                }
                #pragma unroll
                for (int o = 1; o < 16; o <<= 1) {
                    s1[mf][r] += __shfl_xor(s1[mf][r], o);
                    s2[mf][r] += __shfl_xor(s2[mf][r], o);
                }
            }
        }
        float2* lns = (float2*)smem;             // [64 rows][2 col-halves]
        __syncthreads();                         // compute LDS reads done -> reuse
        if (lrow == 0) {
            #pragma unroll
            for (int mf = 0; mf < MF; mf++)
                #pragma unroll
                for (int r = 0; r < 4; r++) {
                    int rl = mw0 + mf * 16 + lk * 4 + r;
                    float2 p; p.x = s1[mf][r]; p.y = s2[mf][r];
                    lns[rl * 2 + wc] = p;
                }
        }
        __syncthreads();
        #pragma unroll
        for (int mf = 0; mf < MF; mf++) {
            #pragma unroll
            for (int r = 0; r < 4; r++) {
                int rl = mw0 + mf * 16 + lk * 4 + r;
                int m = m0 + rl;
                float2 pa = lns[rl * 2 + 0], pb = lns[rl * 2 + 1];
                float mean = (pa.x + pb.x) * (1.0f / 128.0f);
                float var  = (pa.y + pb.y) * (1.0f / 128.0f) - mean * mean;
                float rstd = rsqrtf(var + 1e-5f);
                if (m >= M) continue;
                #pragma unroll
                for (int nf = 0; nf < 4; nf++) {
                    int n = n0 + nf * 16 + lrow;
                    float val = vals[mf][nf][r];
                    ((float*)outp)[(size_t)m * 128 + n] = val;
                    float o = (val - mean) * rstd * lg[n] + lb[n];
                    ((unsigned short*)hbout)[(size_t)m * 128 + n] = f2bf_bits(o);
                }
            }
        }
    }
}

// ---------- node aggregation: one wave per dst node, CSR gather, no atomics ----------
// R5-measured-fast body: x8 unroll (16 gathers in flight), __expf, unscaled q.
__global__ __launch_bounds__(256) void node_agg_k(const bf16* __restrict__ q,
                                                  const bf16* __restrict__ k,
                                                  const bf16* __restrict__ v,
                                                  const int* __restrict__ off,
                                                  const int* __restrict__ deg,
                                                  const int* __restrict__ csr,
                                                  bf16* __restrict__ agg, int NN) {
    int node = blockIdx.x * 4 + (threadIdx.x >> 6);
    if (node >= NN) return;
    int lane = threadIdx.x & 63;
    float2 qf = bfpair(((const unsigned*)(q + (size_t)node * 128))[lane]);
    int start = off[node];
    int cnt = deg[node];
    float acc0 = 0.f, acc1 = 0.f, zsum = 0.f;
    if (cnt < 64) {
        int T = cnt + 1;                                  // + self-loop
        int s_vec = (lane < cnt) ? csr[start + lane] : node;
        for (int e0 = 0; e0 < T; e0 += 8) {
            unsigned ku[8], vu[8];
            #pragma unroll
            for (int j = 0; j < 8; j++) {
                if (e0 + j < T) {
                    int s = __shfl(s_vec, e0 + j);
                    ku[j] = ((const unsigned*)(k + (size_t)s * 128))[lane];
                    vu[j] = ((const unsigned*)(v + (size_t)s * 128))[lane];
                }
            }
            #pragma unroll
            for (int j = 0; j < 8; j++) {
                if (e0 + j < T) {
                    float2 kf = bfpair(ku[j]);
                    float dot = qf.x * kf.x + qf.y * kf.y;
                    dot += __shfl_xor(dot, 1);
                    dot += __shfl_xor(dot, 2);
                    dot += __shfl_xor(dot, 4);            // 8-lane (one head) reduce
                    float p = __expf(dot * 0.25f);
                    zsum += p;
                    float2 vf = bfpair(vu[j]);
                    acc0 += p * vf.x;
                    acc1 += p * vf.y;
                }
            }
        }
    } else {
        for (int e = 0; e <= cnt; e++) {
            int s = (e < cnt) ? csr[start + e] : node;
            float2 kf = bfpair(((const unsigned*)(k + (size_t)s * 128))[lane]);
            float dot = qf.x * kf.x + qf.y * kf.y;
            dot += __shfl_xor(dot, 1);
            dot += __shfl_xor(dot, 2);
            dot += __shfl_xor(dot, 4);
            float p = __expf(dot * 0.25f);
            zsum += p;
            float2 vf = bfpair(((const unsigned*)(v + (size_t)s * 128))[lane]);
            acc0 += p * vf.x;
            acc1 += p * vf.y;
        }
    }
    float2 o;
    if (cnt == 0) { o.x = 0.f; o.y = 0.f; }
    else { float inv = 1.0f / zsum; o.x = acc0 * inv; o.y = acc1 * inv; }
    unsigned pk = ((unsigned)f2bf_bits(o.y) << 16) | (unsigned)f2bf_bits(o.x);
    ((unsigned*)agg)[(size_t)node * 64 + lane] = pk;
}

// ---------- launch ----------
extern "C" void kernel_launch(void* const* d_in, const int* in_sizes, int n_in,
                              void* d_out, int out_size, void* d_ws, size_t ws_size,
                              hipStream_t stream) {
    const float* x  = (const float*)d_in[0];   // fp32, C-order [N,128]
    const void*  eiRaw = d_in[1];
    const float* Wq = (const float*)d_in[2];
    const float* bq = (const float*)d_in[3];
    const float* Wk = (const float*)d_in[4];
    const float* bk = (const float*)d_in[5];
    const float* Wv = (const float*)d_in[6];
    const float* bv = (const float*)d_in[7];
    const float* Wo = (const float*)d_in[8];
    const float* bo = (const float*)d_in[9];
    const float* g1 = (const float*)d_in[10];
    const float* b1 = (const float*)d_in[11];
    const float* g2 = (const float*)d_in[12];
    const float* b2 = (const float*)d_in[13];
    const float* W1 = (const float*)d_in[14];
    const float* bf1 = (const float*)d_in[15];
    const float* W2 = (const float*)d_in[16];
    const float* bf2 = (const float*)d_in[17];
    float* out = (float*)d_out;   // fp32 output; also holds x1

    const int N = in_sizes[0] / 128;
    const int E = in_sizes[1] / 2;
    const int gy = (N + 127) / 128;
    const int gy64 = (N + 63) / 64;
    const int Mp = gy * 128;      // padded row count for GEMM A-operands

    char* w = (char*)d_ws;
    size_t off_b = 0;
    auto alloc = [&](size_t bytes) -> void* {
        void* ptr = w + off_b;
        off_b = (off_b + bytes + 255) & ~(size_t)255;
        return ptr;
    };
    int*   deg    = (int*)alloc((size_t)N * 4);
    int*   offA   = (int*)alloc((size_t)N * 4);
    int*   cursor = (int*)alloc((size_t)N * 4);
    int*   bsum   = (int*)alloc(64 * 4);
    int*   ei32   = (int*)alloc((size_t)E * 2 * 4);
    int*   csr    = (int*)alloc((size_t)E * 4);
    bf16*  hb     = (bf16*)alloc((size_t)Mp * 128 * 2);   // LN1 out; reused for LN2 out
    bf16*  qkvb   = (bf16*)alloc((size_t)N * 3 * 128 * 2);
    bf16*  aggb   = (bf16*)alloc((size_t)Mp * 128 * 2);
    bf16*  t      = (bf16*)alloc((size_t)Mp * 512 * 2);
    unsigned short* qkvH = (unsigned short*)alloc(49152 * 2);
    unsigned short* qkvL = (unsigned short*)alloc(49152 * 2);
    unsigned short* woH  = (unsigned short*)alloc(16384 * 2);
    unsigned short* woL  = (unsigned short*)alloc(16384 * 2);
    unsigned short* w1H  = (unsigned short*)alloc(65536 * 2);
    unsigned short* w1L  = (unsigned short*)alloc(65536 * 2);
    unsigned short* w2H  = (unsigned short*)alloc(65536 * 2);
    unsigned short* w2L  = (unsigned short*)alloc(65536 * 2);
    float* bqkv = (float*)alloc(384 * 4);
    (void)ws_size; (void)n_in; (void)out_size;

    int nb = (N + SCAN_BLK - 1) / SCAN_BLK;
    int nzero = (N + 255) / 256;
    int lnb = (N + 3) / 4;

    // fused setup: weight prep | zero deg | canon edge_index | LN1
    setup_k<<<770 + nzero + 2000 + lnb, 256, 0, stream>>>(
        Wq, Wk, Wv, Wo, W1, W2, bq, bk, bv,
        qkvH, qkvL, woH, woL, w1H, w1L, w2H, w2L, bqkv,
        deg, (const unsigned*)eiRaw, ei32, x, g1, b1, hb, N, E * 2, nzero);
    // CSR build
    count_deg_k<<<(E + 255) / 256, 256, 0, stream>>>(ei32, deg, E);
    scan1_k<<<nb, 256, 0, stream>>>(deg, offA, bsum, N);
    scan3_k<<<(N + 255) / 256, 256, 0, stream>>>(offA, cursor, bsum, N, nb);
    scatter_k<<<(E + 255) / 256, 256, 0, stream>>>(ei32, cursor, csr, E);

    bf16* qb = qkvb;
    bf16* kb = qkvb + (size_t)N * 128;
    bf16* vb = qkvb + (size_t)N * 256;

    // 1. fused QKV GEMM: [q|k|v] = hb @ Wqkv + bqkv (bf16 out, split by n>>7)
    mgemm_k<0, true, 128, 128, false><<<dim3(3, gy), 256, 0, stream>>>(
        hb, (const bf16*)qkvH, (const bf16*)qkvL, bqkv, nullptr, qkvb,
        nullptr, nullptr, nullptr, (long long)N * 128, N, 128, 7);
    // 2. segment softmax + aggregation (bf16 out)
    node_agg_k<<<(N + 3) / 4, 256, 0, stream>>>(qb, kb, vb, offA, deg, csr, aggb, N);
    // 3. x1 = x + aggb @ Wo + bo -> out (fp32), fused LN2 -> hb (bf16)
    mgemm_k<2, false, 128, 64, true><<<dim3(1, gy64), 256, 0, stream>>>(
        aggb, (const bf16*)woH, (const bf16*)woL, bo, x, out,
        g2, b2, hb, 0, N, 128, 15);
    // 4. t = gelu(hb @ W1 + bf1) (bf16)
    mgemm_k<1, true, 128, 128, false><<<dim3(4, gy), 256, 0, stream>>>(
        hb, (const bf16*)w1H, (const bf16*)w1L, bf1, nullptr, t,
        nullptr, nullptr, nullptr, 0, N, 512, 15);
    // 5. out = x1 + t @ W2 + bf2 (fp32; res aliases out elementwise — safe)
    mgemm_k<2, false, 512, 64, false><<<dim3(1, gy64), 256, 0, stream>>>(
        t, (const bf16*)w2H, (const bf16*)w2L, bf2, out, out,
        nullptr, nullptr, nullptr, 0, N, 128, 15);
}

// Round 12
// 461.990 us; speedup vs baseline: 1.0055x; 1.0055x over previous
//
#include <hip/hip_runtime.h>
#include <hip/hip_bf16.h>

typedef __hip_bfloat16 bf16;
typedef __attribute__((ext_vector_type(8))) short s16x8;
typedef __attribute__((ext_vector_type(4))) float f32x4;

// ---------- helpers ----------
__device__ __forceinline__ float2 bfpair(unsigned u) {
    float2 r;
    r.x = __uint_as_float(u << 16);
    r.y = __uint_as_float(u & 0xffff0000u);
    return r;
}

__device__ __forceinline__ unsigned short f2bf_bits(float f) {
    unsigned u = __float_as_uint(f);
    return (unsigned short)((u + 0x7fffu + ((u >> 16) & 1u)) >> 16);
}

// async global->LDS, 16B per lane; LDS dest wave-uniform base (lane*16 implicit)
typedef const __attribute__((address_space(1))) unsigned GU;
typedef __attribute__((address_space(3))) unsigned LU;
__device__ __forceinline__ void gload_lds16(const void* g, void* l) {
    __builtin_amdgcn_global_load_lds((GU*)g, (LU*)l, 16, 0, 0);
}

// ---------- fused setup: prepw (+bias pack) | zero deg | canon ei | LN1 ----------
// block ranges: [0,770) prepw; [770,+nzero) zero deg; [.., +2000) canon; rest LN1
__global__ __launch_bounds__(256) void setup_k(const float* __restrict__ Wq,
                                               const float* __restrict__ Wk,
                                               const float* __restrict__ Wv,
                                               const float* __restrict__ Wo,
                                               const float* __restrict__ W1,
                                               const float* __restrict__ W2,
                                               const float* __restrict__ bq,
                                               const float* __restrict__ bk,
                                               const float* __restrict__ bv,
                                               unsigned short* __restrict__ qkvH,
                                               unsigned short* __restrict__ qkvL,
                                               unsigned short* __restrict__ woH,
                                               unsigned short* __restrict__ woL,
                                               unsigned short* __restrict__ w1H,
                                               unsigned short* __restrict__ w1L,
                                               unsigned short* __restrict__ w2H,
                                               unsigned short* __restrict__ w2L,
                                               float* __restrict__ bqkv,
                                               int* __restrict__ deg,
                                               const unsigned* __restrict__ eisrc,
                                               int* __restrict__ ei32,
                                               const float* __restrict__ x,
                                               const float* __restrict__ g1,
                                               const float* __restrict__ b1,
                                               bf16* __restrict__ hb,
                                               int N, int twoE, int nzero) {
    int b = blockIdx.x;
    int tid = threadIdx.x;
    if (b < 770) {
        int idx = b * 256 + tid;
        if (idx >= 196608) {
            int i = idx - 196608;
            if (i < 384) bqkv[i] = (i < 128) ? bq[i] : (i < 256) ? bk[i - 128] : bv[i - 256];
            return;
        }
        float w; unsigned short *H, *L; int oi;
        if (idx < 49152) {
            int n = idx >> 7, kx = idx & 127;
            const float* W = (n < 128) ? Wq : (n < 256) ? Wk : Wv;
            w = W[kx * 128 + (n & 127)];
            H = qkvH; L = qkvL; oi = idx;
        } else if (idx < 65536) {
            int li = idx - 49152; int n = li >> 7, kx = li & 127;
            w = Wo[kx * 128 + n]; H = woH; L = woL; oi = li;
        } else if (idx < 131072) {
            int li = idx - 65536; int n = li >> 7, kx = li & 127;
            w = W1[(size_t)kx * 512 + n]; H = w1H; L = w1L; oi = li;
        } else {
            int li = idx - 131072; int n = li >> 9, kx = li & 511;
            w = W2[(size_t)kx * 128 + n]; H = w2H; L = w2L; oi = li;
        }
        unsigned short hbits = f2bf_bits(w);
        float hf = __uint_as_float((unsigned)hbits << 16);
        H[oi] = hbits;
        L[oi] = f2bf_bits(w - hf);
        return;
    }
    if (b < 770 + nzero) {
        int i = (b - 770) * 256 + tid;
        if (i < N) deg[i] = 0;
        return;
    }
    if (b < 770 + nzero + 2000) {
        // canon: detect int64 vs int32 (parallel), convert to int32
        __shared__ int s_nz;
        if (tid == 0) s_nz = 0;
        __syncthreads();
        if (eisrc[2 * tid + 1] != 0u) atomicAdd(&s_nz, 1);
        __syncthreads();
        bool is64 = (s_nz == 0);
        long long i = (long long)(b - 770 - nzero) * 256 + tid;
        long long st = (long long)2000 * 256;
        if (is64) { for (; i < twoE; i += st) ei32[i] = (int)eisrc[2 * i]; }
        else      { for (; i < twoE; i += st) ei32[i] = (int)eisrc[i]; }
        return;
    }
    // LN1: one wave per 128-elem row
    int row = (b - 770 - nzero - 2000) * 4 + (tid >> 6);
    if (row >= N) return;
    int lane = tid & 63;
    float2 f = ((const float2*)x)[(size_t)row * 64 + lane];
    float s = f.x + f.y;
    #pragma unroll
    for (int off = 32; off > 0; off >>= 1) s += __shfl_xor(s, off);
    float mean = s * (1.0f / 128.0f);
    float d0 = f.x - mean, d1 = f.y - mean;
    float vs = d0 * d0 + d1 * d1;
    #pragma unroll
    for (int off = 32; off > 0; off >>= 1) vs += __shfl_xor(vs, off);
    float rstd = rsqrtf(vs * (1.0f / 128.0f) + 1e-5f);
    float2 gg = ((const float2*)g1)[lane];
    float2 bb = ((const float2*)b1)[lane];
    float o0 = d0 * rstd * gg.x + bb.x;
    float o1 = d1 * rstd * gg.y + bb.y;
    unsigned pk = ((unsigned)f2bf_bits(o1) << 16) | (unsigned)f2bf_bits(o0);
    ((unsigned*)hb)[(size_t)row * 64 + lane] = pk;
}

// ---------- CSR build ----------
__global__ __launch_bounds__(256) void count_deg_k(const int* __restrict__ ei,
                                                   int* __restrict__ deg, int E) {
    int e = blockIdx.x * 256 + threadIdx.x;
    if (e < E) atomicAdd(&deg[ei[E + e]], 1);
}

#define SCAN_BLK 1024
__global__ __launch_bounds__(256) void scan1_k(const int* __restrict__ deg,
                                               int* __restrict__ off,
                                               int* __restrict__ bsum, int n) {
    __shared__ int s[256];
    int base = blockIdx.x * SCAN_BLK;
    int t = threadIdx.x;
    int v[4]; int sum = 0;
    #pragma unroll
    for (int j = 0; j < 4; j++) {
        int idx = base + t * 4 + j;
        v[j] = (idx < n) ? deg[idx] : 0;
        sum += v[j];
    }
    s[t] = sum; __syncthreads();
    for (int o = 1; o < 256; o <<= 1) {
        int add = (t >= o) ? s[t - o] : 0;
        __syncthreads();
        s[t] += add;
        __syncthreads();
    }
    int run = (t > 0) ? s[t - 1] : 0;
    if (t == 255) bsum[blockIdx.x] = s[255];
    #pragma unroll
    for (int j = 0; j < 4; j++) {
        int idx = base + t * 4 + j;
        if (idx < n) off[idx] = run;
        run += v[j];
    }
}

// scan3 with scan2 (block-sum exclusive prefix) recomputed inline per block
__global__ __launch_bounds__(256) void scan3_k(int* __restrict__ off,
                                               int* __restrict__ cursor,
                                               const int* __restrict__ bsum,
                                               int n, int nb) {
    __shared__ int sb[64];
    int t = threadIdx.x;
    if (t < 64) {
        int own = (t < nb) ? bsum[t] : 0;
        int v = own;
        #pragma unroll
        for (int o = 1; o < 64; o <<= 1) {
            int u = __shfl_up(v, o);
            if ((t & 63) >= o) v += u;
        }
        sb[t] = v - own;   // exclusive
    }
    __syncthreads();
    int i = blockIdx.x * 256 + t;
    if (i < n) {
        int o = off[i] + sb[i / SCAN_BLK];
        off[i] = o;
        cursor[i] = o;
    }
}

__global__ __launch_bounds__(256) void scatter_k(const int* __restrict__ ei,
                                                 int* __restrict__ cursor,
                                                 int* __restrict__ csr, int E) {
    int e = blockIdx.x * 256 + threadIdx.x;
    if (e >= E) return;
    int s = ei[e], d = ei[E + e];
    int pos = atomicAdd(&cursor[d], 1);
    csr[pos] = s;
}

// ---------- MFMA GEMM: A via double-buffered LDS, B direct global->reg ----------
// C[m,n] = A[m,:] @ (Bh+Bl)[n,:] + bias[n] (+gelu / +res / +fused-LN2-out)
// A: bf16 [Mp][K] row-major. B: bf16 [N][K] (pre-transposed), L2-resident (small).
// 256 thr = 4 waves (2x2); block tile BM x 128; wave tile (BM/2) x 64.
// ORDERING (the R11 fix): vmcnt retires in ISSUE order, so B reg-loads are
// issued FIRST each step, then the A-prefetch gload_lds. The compiler's wait
// for B is then vmcnt(#A-loads) and the A-prefetch stays in flight through
// compute; it drains at the next barrier (after overlap), as in the R9 scheme.
template <int EPI, bool OUTBF, int K, int BM, bool LNF>
__global__ __launch_bounds__(256) void mgemm_k(const bf16* __restrict__ A,
                                               const bf16* __restrict__ Bh,
                                               const bf16* __restrict__ Bl,
                                               const float* __restrict__ bias,
                                               const float* __restrict__ res,
                                               void* __restrict__ outp,
                                               const float* __restrict__ lg,
                                               const float* __restrict__ lb,
                                               bf16* __restrict__ hbout,
                                               long long sub_off, int M,
                                               int ldo, int sub_shift) {
    constexpr int MF = BM / 32;                 // 16-row frags per wave in m
    constexpr int NK = K / 32;                  // K-steps
    constexpr int STEP = BM * 64;               // A tile only: BM rows x 64B
    __shared__ __align__(16) char smem[2 * STEP];

    const int lane = threadIdx.x & 63;
    const int wid  = threadIdx.x >> 6;
    const int wr = wid >> 1, wc = wid & 1;
    const int lrow = lane & 15, lk = lane >> 4;  // lk 0..3 = 16B chunk in 64B row
    const int m0 = blockIdx.y * BM;
    const int mw0 = wr * (BM / 2);
    const int n0 = blockIdx.x * 128 + wc * 64;
    const int srow = lane >> 2;                  // staging: row within 16-row group
    const int schunk = (lane & 3) ^ (srow & 3);  // pre-swizzled source chunk

    const char* Ab  = (const char*)A + (size_t)m0 * (K * 2);
    const bf16* Bhp[4]; const bf16* Blp[4];
    #pragma unroll
    for (int nf = 0; nf < 4; nf++) {
        int rb = n0 + nf * 16 + lrow;
        Bhp[nf] = Bh + (size_t)rb * K + lk * 8;
        Blp[nf] = Bl + (size_t)rb * K + lk * 8;
    }

    f32x4 acc[MF][4];
    #pragma unroll
    for (int mf = 0; mf < MF; mf++)
        #pragma unroll
        for (int nf = 0; nf < 4; nf++) {
            f32x4 z = {0.f, 0.f, 0.f, 0.f};
            acc[mf][nf] = z;
        }

    auto stage = [&](int kt, int bufb) {         // A only
        const int kb = kt * 64;                  // byte offset into K
        char* sb = &smem[bufb];
        #pragma unroll
        for (int it = 0; it < BM / 64; it++) {   // 16 rows per instr
            int rg = wid * (BM / 4) + it * 16;
            gload_lds16(Ab + (size_t)(rg + srow) * (K * 2) + kb + schunk * 16,
                        sb + rg * 64);
        }
    };

    stage(0, 0);
    for (int kt = 0; kt < NK; kt++) {
        __syncthreads();                         // buf[kt] staged; WAR-safe for next stage
        // ---- B loads ISSUED FIRST (wait = vmcnt(#A), A-prefetch stays live) ----
        const int ko = kt * 32;
        s16x8 bh[4], bl[4];
        #pragma unroll
        for (int nf = 0; nf < 4; nf++) {
            bh[nf] = *(const s16x8*)(Bhp[nf] + ko);
            bl[nf] = *(const s16x8*)(Blp[nf] + ko);
        }
        // ---- A prefetch for next step, issued after B ----
        if (kt + 1 < NK) stage(kt + 1, ((kt + 1) & 1) * STEP);
        // ---- compute: A frags from LDS, B from regs ----
        {
            const char* sb = &smem[(kt & 1) * STEP];
            s16x8 a[MF];
            #pragma unroll
            for (int mf = 0; mf < MF; mf++) {
                int ra = mw0 + mf * 16 + lrow;
                a[mf] = *(const s16x8*)(sb + ra * 64 + ((lk ^ (ra & 3)) * 16));
            }
            #pragma unroll
            for (int mf = 0; mf < MF; mf++)
                #pragma unroll
                for (int nf = 0; nf < 4; nf++)
                    acc[mf][nf] = __builtin_amdgcn_mfma_f32_16x16x32_bf16(a[mf], bh[nf], acc[mf][nf], 0, 0, 0);
            #pragma unroll
            for (int mf = 0; mf < MF; mf++)
                #pragma unroll
                for (int nf = 0; nf < 4; nf++)
                    acc[mf][nf] = __builtin_amdgcn_mfma_f32_16x16x32_bf16(a[mf], bl[nf], acc[mf][nf], 0, 0, 0);
        }
    }

    if (!LNF) {
        const int nmask = (1 << sub_shift) - 1;
        #pragma unroll
        for (int mf = 0; mf < MF; mf++) {
            #pragma unroll
            for (int nf = 0; nf < 4; nf++) {
                int n = n0 + nf * 16 + lrow;
                float bsv = bias[n];
                #pragma unroll
                for (int r = 0; r < 4; r++) {
                    int m = m0 + mw0 + mf * 16 + lk * 4 + r;
                    if (m >= M) continue;
                    float val = acc[mf][nf][r] + bsv;
                    if (EPI == 1) val = 0.5f * val * (1.0f + erff(val * 0.70710678118f));
                    if (EPI == 2) val += res[(size_t)m * ldo + n];
                    long long oidx = (long long)m * ldo + (n & nmask) + (long long)(n >> sub_shift) * sub_off;
                    if (OUTBF) ((unsigned short*)outp)[oidx] = f2bf_bits(val);
                    else       ((float*)outp)[oidx] = val;
                }
            }
        }
    } else {
        // fused epilogue: out = acc + bias + res (fp32), then LN(out) -> bf16 hbout.
        // BM==64, ldo==128, gx==1: block owns full rows; cross-wave reduce via LDS.
        float vals[MF][4][4];
        float s1[MF][4], s2[MF][4];
        #pragma unroll
        for (int mf = 0; mf < MF; mf++)
            #pragma unroll
            for (int r = 0; r < 4; r++) { s1[mf][r] = 0.f; s2[mf][r] = 0.f; }
        #pragma unroll
        for (int mf = 0; mf < MF; mf++) {
            #pragma unroll
            for (int r = 0; r < 4; r++) {
                int m = m0 + mw0 + mf * 16 + lk * 4 + r;
                #pragma unroll
                for (int nf = 0; nf < 4; nf++) {
                    int n = n0 + nf * 16 + lrow;
                    float val = acc[mf][nf][r] + bias[n];
                    val += (m < M) ? res[(size_t)m * 128 + n] : 0.f;
                    vals[mf][nf][r] = val;
                    s1[mf][r] += val;
                    s2[mf][r] += val * val;
                }
                #pragma unroll
                for (int o = 1; o < 16; o <<= 1) {
                    s1[mf][r] += __shfl_xor(s1[mf][r], o);
                    s2[mf][r] += __shfl_xor(s2[mf][r], o);
                }
            }
        }
        float2* lns = (float2*)smem;             // [64 rows][2 col-halves]
        __syncthreads();                         // compute LDS reads done -> reuse
        if (lrow == 0) {
            #pragma unroll
            for (int mf = 0; mf < MF; mf++)
                #pragma unroll
                for (int r = 0; r < 4; r++) {
                    int rl = mw0 + mf * 16 + lk * 4 + r;
                    float2 p; p.x = s1[mf][r]; p.y = s2[mf][r];
                    lns[rl * 2 + wc] = p;
                }
        }
        __syncthreads();
        #pragma unroll
        for (int mf = 0; mf < MF; mf++) {
            #pragma unroll
            for (int r = 0; r < 4; r++) {
                int rl = mw0 + mf * 16 + lk * 4 + r;
                int m = m0 + rl;
                float2 pa = lns[rl * 2 + 0], pb = lns[rl * 2 + 1];
                float mean = (pa.x + pb.x) * (1.0f / 128.0f);
                float var  = (pa.y + pb.y) * (1.0f / 128.0f) - mean * mean;
                float rstd = rsqrtf(var + 1e-5f);
                if (m >= M) continue;
                #pragma unroll
                for (int nf = 0; nf < 4; nf++) {
                    int n = n0 + nf * 16 + lrow;
                    float val = vals[mf][nf][r];
                    ((float*)outp)[(size_t)m * 128 + n] = val;
                    float o = (val - mean) * rstd * lg[n] + lb[n];
                    ((unsigned short*)hbout)[(size_t)m * 128 + n] = f2bf_bits(o);
                }
            }
        }
    }
}

// ---------- node aggregation: one wave per dst node, CSR gather, no atomics ----------
// R5-measured-fast body: x8 unroll (16 gathers in flight), __expf, unscaled q.
__global__ __launch_bounds__(256) void node_agg_k(const bf16* __restrict__ q,
                                                  const bf16* __restrict__ k,
                                                  const bf16* __restrict__ v,
                                                  const int* __restrict__ off,
                                                  const int* __restrict__ deg,
                                                  const int* __restrict__ csr,
                                                  bf16* __restrict__ agg, int NN) {
    int node = blockIdx.x * 4 + (threadIdx.x >> 6);
    if (node >= NN) return;
    int lane = threadIdx.x & 63;
    float2 qf = bfpair(((const unsigned*)(q + (size_t)node * 128))[lane]);
    int start = off[node];
    int cnt = deg[node];
    float acc0 = 0.f, acc1 = 0.f, zsum = 0.f;
    if (cnt < 64) {
        int T = cnt + 1;                                  // + self-loop
        int s_vec = (lane < cnt) ? csr[start + lane] : node;
        for (int e0 = 0; e0 < T; e0 += 8) {
            unsigned ku[8], vu[8];
            #pragma unroll
            for (int j = 0; j < 8; j++) {
                if (e0 + j < T) {
                    int s = __shfl(s_vec, e0 + j);
                    ku[j] = ((const unsigned*)(k + (size_t)s * 128))[lane];
                    vu[j] = ((const unsigned*)(v + (size_t)s * 128))[lane];
                }
            }
            #pragma unroll
            for (int j = 0; j < 8; j++) {
                if (e0 + j < T) {
                    float2 kf = bfpair(ku[j]);
                    float dot = qf.x * kf.x + qf.y * kf.y;
                    dot += __shfl_xor(dot, 1);
                    dot += __shfl_xor(dot, 2);
                    dot += __shfl_xor(dot, 4);            // 8-lane (one head) reduce
                    float p = __expf(dot * 0.25f);
                    zsum += p;
                    float2 vf = bfpair(vu[j]);
                    acc0 += p * vf.x;
                    acc1 += p * vf.y;
                }
            }
        }
    } else {
        for (int e = 0; e <= cnt; e++) {
            int s = (e < cnt) ? csr[start + e] : node;
            float2 kf = bfpair(((const unsigned*)(k + (size_t)s * 128))[lane]);
            float dot = qf.x * kf.x + qf.y * kf.y;
            dot += __shfl_xor(dot, 1);
            dot += __shfl_xor(dot, 2);
            dot += __shfl_xor(dot, 4);
            float p = __expf(dot * 0.25f);
            zsum += p;
            float2 vf = bfpair(((const unsigned*)(v + (size_t)s * 128))[lane]);
            acc0 += p * vf.x;
            acc1 += p * vf.y;
        }
    }
    float2 o;
    if (cnt == 0) { o.x = 0.f; o.y = 0.f; }
    else { float inv = 1.0f / zsum; o.x = acc0 * inv; o.y = acc1 * inv; }
    unsigned pk = ((unsigned)f2bf_bits(o.y) << 16) | (unsigned)f2bf_bits(o.x);
    ((unsigned*)agg)[(size_t)node * 64 + lane] = pk;
}

// ---------- launch ----------
extern "C" void kernel_launch(void* const* d_in, const int* in_sizes, int n_in,
                              void* d_out, int out_size, void* d_ws, size_t ws_size,
                              hipStream_t stream) {
    const float* x  = (const float*)d_in[0];   // fp32, C-order [N,128]
    const void*  eiRaw = d_in[1];
    const float* Wq = (const float*)d_in[2];
    const float* bq = (const float*)d_in[3];
    const float* Wk = (const float*)d_in[4];
    const float* bk = (const float*)d_in[5];
    const float* Wv = (const float*)d_in[6];
    const float* bv = (const float*)d_in[7];
    const float* Wo = (const float*)d_in[8];
    const float* bo = (const float*)d_in[9];
    const float* g1 = (const float*)d_in[10];
    const float* b1 = (const float*)d_in[11];
    const float* g2 = (const float*)d_in[12];
    const float* b2 = (const float*)d_in[13];
    const float* W1 = (const float*)d_in[14];
    const float* bf1 = (const float*)d_in[15];
    const float* W2 = (const float*)d_in[16];
    const float* bf2 = (const float*)d_in[17];
    float* out = (float*)d_out;   // fp32 output; also holds x1

    const int N = in_sizes[0] / 128;
    const int E = in_sizes[1] / 2;
    const int gy = (N + 127) / 128;
    const int gy64 = (N + 63) / 64;
    const int Mp = gy * 128;      // padded row count for GEMM A-operands

    char* w = (char*)d_ws;
    size_t off_b = 0;
    auto alloc = [&](size_t bytes) -> void* {
        void* ptr = w + off_b;
        off_b = (off_b + bytes + 255) & ~(size_t)255;
        return ptr;
    };
    int*   deg    = (int*)alloc((size_t)N * 4);
    int*   offA   = (int*)alloc((size_t)N * 4);
    int*   cursor = (int*)alloc((size_t)N * 4);
    int*   bsum   = (int*)alloc(64 * 4);
    int*   ei32   = (int*)alloc((size_t)E * 2 * 4);
    int*   csr    = (int*)alloc((size_t)E * 4);
    bf16*  hb     = (bf16*)alloc((size_t)Mp * 128 * 2);   // LN1 out; reused for LN2 out
    bf16*  qkvb   = (bf16*)alloc((size_t)N * 3 * 128 * 2);
    bf16*  aggb   = (bf16*)alloc((size_t)Mp * 128 * 2);
    bf16*  t      = (bf16*)alloc((size_t)Mp * 512 * 2);
    unsigned short* qkvH = (unsigned short*)alloc(49152 * 2);
    unsigned short* qkvL = (unsigned short*)alloc(49152 * 2);
    unsigned short* woH  = (unsigned short*)alloc(16384 * 2);
    unsigned short* woL  = (unsigned short*)alloc(16384 * 2);
    unsigned short* w1H  = (unsigned short*)alloc(65536 * 2);
    unsigned short* w1L  = (unsigned short*)alloc(65536 * 2);
    unsigned short* w2H  = (unsigned short*)alloc(65536 * 2);
    unsigned short* w2L  = (unsigned short*)alloc(65536 * 2);
    float* bqkv = (float*)alloc(384 * 4);
    (void)ws_size; (void)n_in; (void)out_size;

    int nb = (N + SCAN_BLK - 1) / SCAN_BLK;
    int nzero = (N + 255) / 256;
    int lnb = (N + 3) / 4;

    // fused setup: weight prep | zero deg | canon edge_index | LN1
    setup_k<<<770 + nzero + 2000 + lnb, 256, 0, stream>>>(
        Wq, Wk, Wv, Wo, W1, W2, bq, bk, bv,
        qkvH, qkvL, woH, woL, w1H, w1L, w2H, w2L, bqkv,
        deg, (const unsigned*)eiRaw, ei32, x, g1, b1, hb, N, E * 2, nzero);
    // CSR build
    count_deg_k<<<(E + 255) / 256, 256, 0, stream>>>(ei32, deg, E);
    scan1_k<<<nb, 256, 0, stream>>>(deg, offA, bsum, N);
    scan3_k<<<(N + 255) / 256, 256, 0, stream>>>(offA, cursor, bsum, N, nb);
    scatter_k<<<(E + 255) / 256, 256, 0, stream>>>(ei32, cursor, csr, E);

    bf16* qb = qkvb;
    bf16* kb = qkvb + (size_t)N * 128;
    bf16* vb = qkvb + (size_t)N * 256;

    // 1. fused QKV GEMM: [q|k|v] = hb @ Wqkv + bqkv (bf16 out, split by n>>7)
    mgemm_k<0, true, 128, 128, false><<<dim3(3, gy), 256, 0, stream>>>(
        hb, (const bf16*)qkvH, (const bf16*)qkvL, bqkv, nullptr, qkvb,
        nullptr, nullptr, nullptr, (long long)N * 128, N, 128, 7);
    // 2. segment softmax + aggregation (bf16 out)
    node_agg_k<<<(N + 3) / 4, 256, 0, stream>>>(qb, kb, vb, offA, deg, csr, aggb, N);
    // 3. x1 = x + aggb @ Wo + bo -> out (fp32), fused LN2 -> hb (bf16)
    mgemm_k<2, false, 128, 64, true><<<dim3(1, gy64), 256, 0, stream>>>(
        aggb, (const bf16*)woH, (const bf16*)woL, bo, x, out,
        g2, b2, hb, 0, N, 128, 15);
    // 4. t = gelu(hb @ W1 + bf1) (bf16)
    mgemm_k<1, true, 128, 128, false><<<dim3(4, gy), 256, 0, stream>>>(
        hb, (const bf16*)w1H, (const bf16*)w1L, bf1, nullptr, t,
        nullptr, nullptr, nullptr, 0, N, 512, 15);
    // 5. out = x1 + t @ W2 + bf2 (fp32; res aliases out elementwise — safe)
    mgemm_k<2, false, 512, 64, false><<<dim3(1, gy64), 256, 0, stream>>>(
        t, (const bf16*)w2H, (const bf16*)w2L, bf2, out, out,
        nullptr, nullptr, nullptr, 0, N, 128, 15);
}

// Round 13
// 396.716 us; speedup vs baseline: 1.1709x; 1.1645x over previous
//
#include <hip/hip_runtime.h>
#include <hip/hip_bf16.h>

typedef __hip_bfloat16 bf16;
typedef __attribute__((ext_vector_type(8))) short s16x8;
typedef __attribute__((ext_vector_type(4))) float f32x4;

// ---------- helpers ----------
__device__ __forceinline__ float2 bfpair(unsigned u) {
    float2 r;
    r.x = __uint_as_float(u << 16);
    r.y = __uint_as_float(u & 0xffff0000u);
    return r;
}

__device__ __forceinline__ unsigned short f2bf_bits(float f) {
    unsigned u = __float_as_uint(f);
    return (unsigned short)((u + 0x7fffu + ((u >> 16) & 1u)) >> 16);
}

// async global->LDS, 16B per lane; LDS dest wave-uniform base (lane*16 implicit)
typedef const __attribute__((address_space(1))) unsigned GU;
typedef __attribute__((address_space(3))) unsigned LU;
__device__ __forceinline__ void gload_lds16(const void* g, void* l) {
    __builtin_amdgcn_global_load_lds((GU*)g, (LU*)l, 16, 0, 0);
}

// ---------- fused setup: prepw (+bias pack) | zero deg | canon ei | LN1 ----------
// block ranges: [0,770) prepw; [770,+nzero) zero deg; [.., +2000) canon; rest LN1
__global__ __launch_bounds__(256) void setup_k(const float* __restrict__ Wq,
                                               const float* __restrict__ Wk,
                                               const float* __restrict__ Wv,
                                               const float* __restrict__ Wo,
                                               const float* __restrict__ W1,
                                               const float* __restrict__ W2,
                                               const float* __restrict__ bq,
                                               const float* __restrict__ bk,
                                               const float* __restrict__ bv,
                                               unsigned short* __restrict__ qkvH,
                                               unsigned short* __restrict__ qkvL,
                                               unsigned short* __restrict__ woH,
                                               unsigned short* __restrict__ woL,
                                               unsigned short* __restrict__ w1H,
                                               unsigned short* __restrict__ w1L,
                                               unsigned short* __restrict__ w2H,
                                               unsigned short* __restrict__ w2L,
                                               float* __restrict__ bqkv,
                                               int* __restrict__ deg,
                                               const unsigned* __restrict__ eisrc,
                                               int* __restrict__ ei32,
                                               const float* __restrict__ x,
                                               const float* __restrict__ g1,
                                               const float* __restrict__ b1,
                                               bf16* __restrict__ hb,
                                               int N, int twoE, int nzero) {
    int b = blockIdx.x;
    int tid = threadIdx.x;
    if (b < 770) {
        int idx = b * 256 + tid;
        if (idx >= 196608) {
            int i = idx - 196608;
            if (i < 384) bqkv[i] = (i < 128) ? bq[i] : (i < 256) ? bk[i - 128] : bv[i - 256];
            return;
        }
        float w; unsigned short *H, *L; int oi;
        if (idx < 49152) {
            int n = idx >> 7, kx = idx & 127;
            const float* W = (n < 128) ? Wq : (n < 256) ? Wk : Wv;
            w = W[kx * 128 + (n & 127)];
            H = qkvH; L = qkvL; oi = idx;
        } else if (idx < 65536) {
            int li = idx - 49152; int n = li >> 7, kx = li & 127;
            w = Wo[kx * 128 + n]; H = woH; L = woL; oi = li;
        } else if (idx < 131072) {
            int li = idx - 65536; int n = li >> 7, kx = li & 127;
            w = W1[(size_t)kx * 512 + n]; H = w1H; L = w1L; oi = li;
        } else {
            int li = idx - 131072; int n = li >> 9, kx = li & 511;
            w = W2[(size_t)kx * 128 + n]; H = w2H; L = w2L; oi = li;
        }
        unsigned short hbits = f2bf_bits(w);
        float hf = __uint_as_float((unsigned)hbits << 16);
        H[oi] = hbits;
        L[oi] = f2bf_bits(w - hf);
        return;
    }
    if (b < 770 + nzero) {
        int i = (b - 770) * 256 + tid;
        if (i < N) deg[i] = 0;
        return;
    }
    if (b < 770 + nzero + 2000) {
        // canon: detect int64 vs int32 (parallel), convert to int32
        __shared__ int s_nz;
        if (tid == 0) s_nz = 0;
        __syncthreads();
        if (eisrc[2 * tid + 1] != 0u) atomicAdd(&s_nz, 1);
        __syncthreads();
        bool is64 = (s_nz == 0);
        long long i = (long long)(b - 770 - nzero) * 256 + tid;
        long long st = (long long)2000 * 256;
        if (is64) { for (; i < twoE; i += st) ei32[i] = (int)eisrc[2 * i]; }
        else      { for (; i < twoE; i += st) ei32[i] = (int)eisrc[i]; }
        return;
    }
    // LN1: one wave per 128-elem row
    int row = (b - 770 - nzero - 2000) * 4 + (tid >> 6);
    if (row >= N) return;
    int lane = tid & 63;
    float2 f = ((const float2*)x)[(size_t)row * 64 + lane];
    float s = f.x + f.y;
    #pragma unroll
    for (int off = 32; off > 0; off >>= 1) s += __shfl_xor(s, off);
    float mean = s * (1.0f / 128.0f);
    float d0 = f.x - mean, d1 = f.y - mean;
    float vs = d0 * d0 + d1 * d1;
    #pragma unroll
    for (int off = 32; off > 0; off >>= 1) vs += __shfl_xor(vs, off);
    float rstd = rsqrtf(vs * (1.0f / 128.0f) + 1e-5f);
    float2 gg = ((const float2*)g1)[lane];
    float2 bb = ((const float2*)b1)[lane];
    float o0 = d0 * rstd * gg.x + bb.x;
    float o1 = d1 * rstd * gg.y + bb.y;
    unsigned pk = ((unsigned)f2bf_bits(o1) << 16) | (unsigned)f2bf_bits(o0);
    ((unsigned*)hb)[(size_t)row * 64 + lane] = pk;
}

// ---------- CSR build ----------
__global__ __launch_bounds__(256) void count_deg_k(const int* __restrict__ ei,
                                                   int* __restrict__ deg, int E) {
    int e = blockIdx.x * 256 + threadIdx.x;
    if (e < E) atomicAdd(&deg[ei[E + e]], 1);
}

#define SCAN_BLK 1024
__global__ __launch_bounds__(256) void scan1_k(const int* __restrict__ deg,
                                               int* __restrict__ off,
                                               int* __restrict__ bsum, int n) {
    __shared__ int s[256];
    int base = blockIdx.x * SCAN_BLK;
    int t = threadIdx.x;
    int v[4]; int sum = 0;
    #pragma unroll
    for (int j = 0; j < 4; j++) {
        int idx = base + t * 4 + j;
        v[j] = (idx < n) ? deg[idx] : 0;
        sum += v[j];
    }
    s[t] = sum; __syncthreads();
    for (int o = 1; o < 256; o <<= 1) {
        int add = (t >= o) ? s[t - o] : 0;
        __syncthreads();
        s[t] += add;
        __syncthreads();
    }
    int run = (t > 0) ? s[t - 1] : 0;
    if (t == 255) bsum[blockIdx.x] = s[255];
    #pragma unroll
    for (int j = 0; j < 4; j++) {
        int idx = base + t * 4 + j;
        if (idx < n) off[idx] = run;
        run += v[j];
    }
}

// scan3 with scan2 (block-sum exclusive prefix) recomputed inline per block
__global__ __launch_bounds__(256) void scan3_k(int* __restrict__ off,
                                               int* __restrict__ cursor,
                                               const int* __restrict__ bsum,
                                               int n, int nb) {
    __shared__ int sb[64];
    int t = threadIdx.x;
    if (t < 64) {
        int own = (t < nb) ? bsum[t] : 0;
        int v = own;
        #pragma unroll
        for (int o = 1; o < 64; o <<= 1) {
            int u = __shfl_up(v, o);
            if ((t & 63) >= o) v += u;
        }
        sb[t] = v - own;   // exclusive
    }
    __syncthreads();
    int i = blockIdx.x * 256 + t;
    if (i < n) {
        int o = off[i] + sb[i / SCAN_BLK];
        off[i] = o;
        cursor[i] = o;
    }
}

__global__ __launch_bounds__(256) void scatter_k(const int* __restrict__ ei,
                                                 int* __restrict__ cursor,
                                                 int* __restrict__ csr, int E) {
    int e = blockIdx.x * 256 + threadIdx.x;
    if (e >= E) return;
    int s = ei[e], d = ei[E + e];
    int pos = atomicAdd(&cursor[d], 1);
    csr[pos] = s;
}

// ---------- MFMA GEMM, pipelined double-buffered LDS (BK=32, 1 barrier/step) ----------
// C[m,n] = A[m,:] @ (Bh+Bl)[n,:] + bias[n] (+gelu / +res / +fused-LN2-out)
// A: bf16 [Mp][K] row-major. B: bf16 [N][K] (pre-transposed).
// 256 thr = 4 waves (2x2); block tile BM x 128; wave tile (BM/2) x 64.
// Pipeline: stage(0); for kt: sync; stage(kt+1, buf^1); compute(kt, buf).
// Swizzle (both-sides): 64B LDS rows of 4x16B chunks; slot = chunk ^ ((row>>1)&3)
// -> frag reads hit 8 distinct bank groups (2-way = free; the old row&3 swizzle
// was 4-way = 1.58x, R10 profile: 1.2M conflict cycles). Staged via pre-swizzled
// global source (linear LDS dest), read with the same XOR.
template <int EPI, bool OUTBF, int K, int BM, bool LNF>
__global__ __launch_bounds__(256) void mgemm_k(const bf16* __restrict__ A,
                                               const bf16* __restrict__ Bh,
                                               const bf16* __restrict__ Bl,
                                               const float* __restrict__ bias,
                                               const float* __restrict__ res,
                                               void* __restrict__ outp,
                                               const float* __restrict__ lg,
                                               const float* __restrict__ lb,
                                               bf16* __restrict__ hbout,
                                               long long sub_off, int M,
                                               int ldo, int sub_shift) {
    constexpr int MF = BM / 32;                 // 16-row frags per wave in m
    constexpr int NK = K / 32;                  // K-steps
    constexpr int STEP = BM * 64 + 2 * 8192;    // A(BM x 64B) + Bh(8K) + Bl(8K)
    __shared__ __align__(16) char smem[2 * STEP];

    const int lane = threadIdx.x & 63;
    const int wid  = threadIdx.x >> 6;
    const int wr = wid >> 1, wc = wid & 1;
    const int lrow = lane & 15, lk = lane >> 4;  // lk 0..3 = 16B chunk in 64B row
    const int m0 = blockIdx.y * BM;
    const int mw0 = wr * (BM / 2);
    const int n0 = blockIdx.x * 128 + wc * 64;
    const int srow = lane >> 2;                  // staging: row within 16-row group
    const int schunk = (lane & 3) ^ ((srow >> 1) & 3);  // pre-swizzled source chunk

    const char* Ab  = (const char*)A  + (size_t)m0 * (K * 2);
    const char* Bhb = (const char*)Bh + (size_t)(blockIdx.x * 128) * (K * 2);
    const char* Blb = (const char*)Bl + (size_t)(blockIdx.x * 128) * (K * 2);

    f32x4 acc[MF][4];
    #pragma unroll
    for (int mf = 0; mf < MF; mf++)
        #pragma unroll
        for (int nf = 0; nf < 4; nf++) {
            f32x4 z = {0.f, 0.f, 0.f, 0.f};
            acc[mf][nf] = z;
        }

    auto stage = [&](int kt, int bufb) {
        const int kb = kt * 64;                  // byte offset into K
        char* sb = &smem[bufb];
        #pragma unroll
        for (int it = 0; it < BM / 64; it++) {   // A: 16 rows per instr
            int rg = wid * (BM / 4) + it * 16;
            gload_lds16(Ab + (size_t)(rg + srow) * (K * 2) + kb + schunk * 16,
                        sb + rg * 64);
        }
        #pragma unroll
        for (int it = 0; it < 2; it++) {         // Bh/Bl: 128 rows each
            int rg = wid * 32 + it * 16;
            gload_lds16(Bhb + (size_t)(rg + srow) * (K * 2) + kb + schunk * 16,
                        sb + BM * 64 + rg * 64);
            gload_lds16(Blb + (size_t)(rg + srow) * (K * 2) + kb + schunk * 16,
                        sb + BM * 64 + 8192 + rg * 64);
        }
    };

    auto compute = [&](int bufb) {
        const char* sb = &smem[bufb];
        s16x8 a[MF], bh[4], bl[4];
        #pragma unroll
        for (int mf = 0; mf < MF; mf++) {
            int ra = mw0 + mf * 16 + lrow;
            a[mf] = *(const s16x8*)(sb + ra * 64 + ((lk ^ ((ra >> 1) & 3)) * 16));
        }
        #pragma unroll
        for (int nf = 0; nf < 4; nf++) {
            int rb = wc * 64 + nf * 16 + lrow;
            int co = (lk ^ ((rb >> 1) & 3)) * 16;
            bh[nf] = *(const s16x8*)(sb + BM * 64 + rb * 64 + co);
            bl[nf] = *(const s16x8*)(sb + BM * 64 + 8192 + rb * 64 + co);
        }
        #pragma unroll
        for (int mf = 0; mf < MF; mf++)
            #pragma unroll
            for (int nf = 0; nf < 4; nf++)
                acc[mf][nf] = __builtin_amdgcn_mfma_f32_16x16x32_bf16(a[mf], bh[nf], acc[mf][nf], 0, 0, 0);
        #pragma unroll
        for (int mf = 0; mf < MF; mf++)
            #pragma unroll
            for (int nf = 0; nf < 4; nf++)
                acc[mf][nf] = __builtin_amdgcn_mfma_f32_16x16x32_bf16(a[mf], bl[nf], acc[mf][nf], 0, 0, 0);
    };

    stage(0, 0);
    for (int kt = 0; kt < NK; kt++) {
        __syncthreads();                         // buf[kt] staged; WAR-safe for next stage
        if (kt + 1 < NK) stage(kt + 1, ((kt + 1) & 1) * STEP);
        compute((kt & 1) * STEP);
    }

    if (!LNF) {
        const int nmask = (1 << sub_shift) - 1;
        #pragma unroll
        for (int mf = 0; mf < MF; mf++) {
            #pragma unroll
            for (int nf = 0; nf < 4; nf++) {
                int n = n0 + nf * 16 + lrow;
                float bsv = bias[n];
                #pragma unroll
                for (int r = 0; r < 4; r++) {
                    int m = m0 + mw0 + mf * 16 + lk * 4 + r;
                    if (m >= M) continue;
                    float val = acc[mf][nf][r] + bsv;
                    if (EPI == 1) val = 0.5f * val * (1.0f + erff(val * 0.70710678118f));
                    if (EPI == 2) val += res[(size_t)m * ldo + n];
                    long long oidx = (long long)m * ldo + (n & nmask) + (long long)(n >> sub_shift) * sub_off;
                    if (OUTBF) ((unsigned short*)outp)[oidx] = f2bf_bits(val);
                    else       ((float*)outp)[oidx] = val;
                }
            }
        }
    } else {
        // fused epilogue: out = acc + bias + res (fp32), then LN(out) -> bf16 hbout.
        // BM==64, ldo==128, gx==1: block owns full rows; cross-wave reduce via LDS.
        float vals[MF][4][4];
        float s1[MF][4], s2[MF][4];
        #pragma unroll
        for (int mf = 0; mf < MF; mf++)
            #pragma unroll
            for (int r = 0; r < 4; r++) { s1[mf][r] = 0.f; s2[mf][r] = 0.f; }
        #pragma unroll
        for (int mf = 0; mf < MF; mf++) {
            #pragma unroll
            for (int r = 0; r < 4; r++) {
                int m = m0 + mw0 + mf * 16 + lk * 4 + r;
                #pragma unroll
                for (int nf = 0; nf < 4; nf++) {
                    int n = n0 + nf * 16 + lrow;
                    float val = acc[mf][nf][r] + bias[n];
                    val += (m < M) ? res[(size_t)m * 128 + n] : 0.f;
                    vals[mf][nf][r] = val;
                    s1[mf][r] += val;
                    s2[mf][r] += val * val;
                }
                #pragma unroll
                for (int o = 1; o < 16; o <<= 1) {
                    s1[mf][r] += __shfl_xor(s1[mf][r], o);
                    s2[mf][r] += __shfl_xor(s2[mf][r], o);
                }
            }
        }
        float2* lns = (float2*)smem;             // [64 rows][2 col-halves]
        __syncthreads();                         // compute LDS reads done -> reuse
        if (lrow == 0) {
            #pragma unroll
            for (int mf = 0; mf < MF; mf++)
                #pragma unroll
                for (int r = 0; r < 4; r++) {
                    int rl = mw0 + mf * 16 + lk * 4 + r;
                    float2 p; p.x = s1[mf][r]; p.y = s2[mf][r];
                    lns[rl * 2 + wc] = p;
                }
        }
        __syncthreads();
        #pragma unroll
        for (int mf = 0; mf < MF; mf++) {
            #pragma unroll
            for (int r = 0; r < 4; r++) {
                int rl = mw0 + mf * 16 + lk * 4 + r;
                int m = m0 + rl;
                float2 pa = lns[rl * 2 + 0], pb = lns[rl * 2 + 1];
                float mean = (pa.x + pb.x) * (1.0f / 128.0f);
                float var  = (pa.y + pb.y) * (1.0f / 128.0f) - mean * mean;
                float rstd = rsqrtf(var + 1e-5f);
                if (m >= M) continue;
                #pragma unroll
                for (int nf = 0; nf < 4; nf++) {
                    int n = n0 + nf * 16 + lrow;
                    float val = vals[mf][nf][r];
                    ((float*)outp)[(size_t)m * 128 + n] = val;
                    float o = (val - mean) * rstd * lg[n] + lb[n];
                    ((unsigned short*)hbout)[(size_t)m * 128 + n] = f2bf_bits(o);
                }
            }
        }
    }
}

// ---------- node aggregation: one wave per dst node, CSR gather, no atomics ----------
// R5-measured-fast body: x8 unroll (16 gathers in flight), __expf, unscaled q.
__global__ __launch_bounds__(256) void node_agg_k(const bf16* __restrict__ q,
                                                  const bf16* __restrict__ k,
                                                  const bf16* __restrict__ v,
                                                  const int* __restrict__ off,
                                                  const int* __restrict__ deg,
                                                  const int* __restrict__ csr,
                                                  bf16* __restrict__ agg, int NN) {
    int node = blockIdx.x * 4 + (threadIdx.x >> 6);
    if (node >= NN) return;
    int lane = threadIdx.x & 63;
    float2 qf = bfpair(((const unsigned*)(q + (size_t)node * 128))[lane]);
    int start = off[node];
    int cnt = deg[node];
    float acc0 = 0.f, acc1 = 0.f, zsum = 0.f;
    if (cnt < 64) {
        int T = cnt + 1;                                  // + self-loop
        int s_vec = (lane < cnt) ? csr[start + lane] : node;
        for (int e0 = 0; e0 < T; e0 += 8) {
            unsigned ku[8], vu[8];
            #pragma unroll
            for (int j = 0; j < 8; j++) {
                if (e0 + j < T) {
                    int s = __shfl(s_vec, e0 + j);
                    ku[j] = ((const unsigned*)(k + (size_t)s * 128))[lane];
                    vu[j] = ((const unsigned*)(v + (size_t)s * 128))[lane];
                }
            }
            #pragma unroll
            for (int j = 0; j < 8; j++) {
                if (e0 + j < T) {
                    float2 kf = bfpair(ku[j]);
                    float dot = qf.x * kf.x + qf.y * kf.y;
                    dot += __shfl_xor(dot, 1);
                    dot += __shfl_xor(dot, 2);
                    dot += __shfl_xor(dot, 4);            // 8-lane (one head) reduce
                    float p = __expf(dot * 0.25f);
                    zsum += p;
                    float2 vf = bfpair(vu[j]);
                    acc0 += p * vf.x;
                    acc1 += p * vf.y;
                }
            }
        }
    } else {
        for (int e = 0; e <= cnt; e++) {
            int s = (e < cnt) ? csr[start + e] : node;
            float2 kf = bfpair(((const unsigned*)(k + (size_t)s * 128))[lane]);
            float dot = qf.x * kf.x + qf.y * kf.y;
            dot += __shfl_xor(dot, 1);
            dot += __shfl_xor(dot, 2);
            dot += __shfl_xor(dot, 4);
            float p = __expf(dot * 0.25f);
            zsum += p;
            float2 vf = bfpair(((const unsigned*)(v + (size_t)s * 128))[lane]);
            acc0 += p * vf.x;
            acc1 += p * vf.y;
        }
    }
    float2 o;
    if (cnt == 0) { o.x = 0.f; o.y = 0.f; }
    else { float inv = 1.0f / zsum; o.x = acc0 * inv; o.y = acc1 * inv; }
    unsigned pk = ((unsigned)f2bf_bits(o.y) << 16) | (unsigned)f2bf_bits(o.x);
    ((unsigned*)agg)[(size_t)node * 64 + lane] = pk;
}

// ---------- launch ----------
extern "C" void kernel_launch(void* const* d_in, const int* in_sizes, int n_in,
                              void* d_out, int out_size, void* d_ws, size_t ws_size,
                              hipStream_t stream) {
    const float* x  = (const float*)d_in[0];   // fp32, C-order [N,128]
    const void*  eiRaw = d_in[1];
    const float* Wq = (const float*)d_in[2];
    const float* bq = (const float*)d_in[3];
    const float* Wk = (const float*)d_in[4];
    const float* bk = (const float*)d_in[5];
    const float* Wv = (const float*)d_in[6];
    const float* bv = (const float*)d_in[7];
    const float* Wo = (const float*)d_in[8];
    const float* bo = (const float*)d_in[9];
    const float* g1 = (const float*)d_in[10];
    const float* b1 = (const float*)d_in[11];
    const float* g2 = (const float*)d_in[12];
    const float* b2 = (const float*)d_in[13];
    const float* W1 = (const float*)d_in[14];
    const float* bf1 = (const float*)d_in[15];
    const float* W2 = (const float*)d_in[16];
    const float* bf2 = (const float*)d_in[17];
    float* out = (float*)d_out;   // fp32 output; also holds x1

    const int N = in_sizes[0] / 128;
    const int E = in_sizes[1] / 2;
    const int gy = (N + 127) / 128;
    const int gy64 = (N + 63) / 64;
    const int Mp = gy * 128;      // padded row count for GEMM A-operands

    char* w = (char*)d_ws;
    size_t off_b = 0;
    auto alloc = [&](size_t bytes) -> void* {
        void* ptr = w + off_b;
        off_b = (off_b + bytes + 255) & ~(size_t)255;
        return ptr;
    };
    int*   deg    = (int*)alloc((size_t)N * 4);
    int*   offA   = (int*)alloc((size_t)N * 4);
    int*   cursor = (int*)alloc((size_t)N * 4);
    int*   bsum   = (int*)alloc(64 * 4);
    int*   ei32   = (int*)alloc((size_t)E * 2 * 4);
    int*   csr    = (int*)alloc((size_t)E * 4);
    bf16*  hb     = (bf16*)alloc((size_t)Mp * 128 * 2);   // LN1 out; reused for LN2 out
    bf16*  qkvb   = (bf16*)alloc((size_t)N * 3 * 128 * 2);
    bf16*  aggb   = (bf16*)alloc((size_t)Mp * 128 * 2);
    bf16*  t      = (bf16*)alloc((size_t)Mp * 512 * 2);
    unsigned short* qkvH = (unsigned short*)alloc(49152 * 2);
    unsigned short* qkvL = (unsigned short*)alloc(49152 * 2);
    unsigned short* woH  = (unsigned short*)alloc(16384 * 2);
    unsigned short* woL  = (unsigned short*)alloc(16384 * 2);
    unsigned short* w1H  = (unsigned short*)alloc(65536 * 2);
    unsigned short* w1L  = (unsigned short*)alloc(65536 * 2);
    unsigned short* w2H  = (unsigned short*)alloc(65536 * 2);
    unsigned short* w2L  = (unsigned short*)alloc(65536 * 2);
    float* bqkv = (float*)alloc(384 * 4);
    (void)ws_size; (void)n_in; (void)out_size;

    int nb = (N + SCAN_BLK - 1) / SCAN_BLK;
    int nzero = (N + 255) / 256;
    int lnb = (N + 3) / 4;

    // fused setup: weight prep | zero deg | canon edge_index | LN1
    setup_k<<<770 + nzero + 2000 + lnb, 256, 0, stream>>>(
        Wq, Wk, Wv, Wo, W1, W2, bq, bk, bv,
        qkvH, qkvL, woH, woL, w1H, w1L, w2H, w2L, bqkv,
        deg, (const unsigned*)eiRaw, ei32, x, g1, b1, hb, N, E * 2, nzero);
    // CSR build
    count_deg_k<<<(E + 255) / 256, 256, 0, stream>>>(ei32, deg, E);
    scan1_k<<<nb, 256, 0, stream>>>(deg, offA, bsum, N);
    scan3_k<<<(N + 255) / 256, 256, 0, stream>>>(offA, cursor, bsum, N, nb);
    scatter_k<<<(E + 255) / 256, 256, 0, stream>>>(ei32, cursor, csr, E);

    bf16* qb = qkvb;
    bf16* kb = qkvb + (size_t)N * 128;
    bf16* vb = qkvb + (size_t)N * 256;

    // 1. fused QKV GEMM: [q|k|v] = hb @ Wqkv + bqkv (bf16 out, split by n>>7)
    mgemm_k<0, true, 128, 128, false><<<dim3(3, gy), 256, 0, stream>>>(
        hb, (const bf16*)qkvH, (const bf16*)qkvL, bqkv, nullptr, qkvb,
        nullptr, nullptr, nullptr, (long long)N * 128, N, 128, 7);
    // 2. segment softmax + aggregation (bf16 out)
    node_agg_k<<<(N + 3) / 4, 256, 0, stream>>>(qb, kb, vb, offA, deg, csr, aggb, N);
    // 3. x1 = x + aggb @ Wo + bo -> out (fp32), fused LN2 -> hb (bf16)
    mgemm_k<2, false, 128, 64, true><<<dim3(1, gy64), 256, 0, stream>>>(
        aggb, (const bf16*)woH, (const bf16*)woL, bo, x, out,
        g2, b2, hb, 0, N, 128, 15);
    // 4. t = gelu(hb @ W1 + bf1) (bf16)
    mgemm_k<1, true, 128, 128, false><<<dim3(4, gy), 256, 0, stream>>>(
        hb, (const bf16*)w1H, (const bf16*)w1L, bf1, nullptr, t,
        nullptr, nullptr, nullptr, 0, N, 512, 15);
    // 5. out = x1 + t @ W2 + bf2 (fp32; res aliases out elementwise — safe)
    mgemm_k<2, false, 512, 64, false><<<dim3(1, gy64), 256, 0, stream>>>(
        t, (const bf16*)w2H, (const bf16*)w2L, bf2, out, out,
        nullptr, nullptr, nullptr, 0, N, 128, 15);
}

// Round 14
// 389.529 us; speedup vs baseline: 1.1925x; 1.0184x over previous
//
#include <hip/hip_runtime.h>
#include <hip/hip_bf16.h>

typedef __hip_bfloat16 bf16;
typedef __attribute__((ext_vector_type(8))) short s16x8;
typedef __attribute__((ext_vector_type(4))) float f32x4;

// ---------- helpers ----------
__device__ __forceinline__ float2 bfpair(unsigned u) {
    float2 r;
    r.x = __uint_as_float(u << 16);
    r.y = __uint_as_float(u & 0xffff0000u);
    return r;
}

__device__ __forceinline__ unsigned short f2bf_bits(float f) {
    unsigned u = __float_as_uint(f);
    return (unsigned short)((u + 0x7fffu + ((u >> 16) & 1u)) >> 16);
}

// async global->LDS, 16B per lane; LDS dest wave-uniform base (lane*16 implicit)
typedef const __attribute__((address_space(1))) unsigned GU;
typedef __attribute__((address_space(3))) unsigned LU;
__device__ __forceinline__ void gload_lds16(const void* g, void* l) {
    __builtin_amdgcn_global_load_lds((GU*)g, (LU*)l, 16, 0, 0);
}

// ---------- fused setup: prepw (+bias pack) | zero deg | canon ei | LN1 ----------
// block ranges: [0,770) prepw; [770,+nzero) zero deg; [.., +2000) canon; rest LN1
// Weights: single bf16 (no hi/lo split — weight-quant error ~1e-4 abs, 300x below
// the attention-path bf16 staging error that sets absmax).
__global__ __launch_bounds__(256) void setup_k(const float* __restrict__ Wq,
                                               const float* __restrict__ Wk,
                                               const float* __restrict__ Wv,
                                               const float* __restrict__ Wo,
                                               const float* __restrict__ W1,
                                               const float* __restrict__ W2,
                                               const float* __restrict__ bq,
                                               const float* __restrict__ bk,
                                               const float* __restrict__ bv,
                                               unsigned short* __restrict__ qkvH,
                                               unsigned short* __restrict__ woH,
                                               unsigned short* __restrict__ w1H,
                                               unsigned short* __restrict__ w2H,
                                               float* __restrict__ bqkv,
                                               int* __restrict__ deg,
                                               const unsigned* __restrict__ eisrc,
                                               int* __restrict__ ei32,
                                               const float* __restrict__ x,
                                               const float* __restrict__ g1,
                                               const float* __restrict__ b1,
                                               bf16* __restrict__ hb,
                                               int N, int twoE, int nzero) {
    int b = blockIdx.x;
    int tid = threadIdx.x;
    if (b < 770) {
        int idx = b * 256 + tid;
        if (idx >= 196608) {
            int i = idx - 196608;
            if (i < 384) bqkv[i] = (i < 128) ? bq[i] : (i < 256) ? bk[i - 128] : bv[i - 256];
            return;
        }
        float w; unsigned short *H; int oi;
        if (idx < 49152) {
            int n = idx >> 7, kx = idx & 127;
            const float* W = (n < 128) ? Wq : (n < 256) ? Wk : Wv;
            w = W[kx * 128 + (n & 127)];
            H = qkvH; oi = idx;
        } else if (idx < 65536) {
            int li = idx - 49152; int n = li >> 7, kx = li & 127;
            w = Wo[kx * 128 + n]; H = woH; oi = li;
        } else if (idx < 131072) {
            int li = idx - 65536; int n = li >> 7, kx = li & 127;
            w = W1[(size_t)kx * 512 + n]; H = w1H; oi = li;
        } else {
            int li = idx - 131072; int n = li >> 9, kx = li & 511;
            w = W2[(size_t)kx * 128 + n]; H = w2H; oi = li;
        }
        H[oi] = f2bf_bits(w);
        return;
    }
    if (b < 770 + nzero) {
        int i = (b - 770) * 256 + tid;
        if (i < N) deg[i] = 0;
        return;
    }
    if (b < 770 + nzero + 2000) {
        // canon: detect int64 vs int32 (parallel), convert to int32
        __shared__ int s_nz;
        if (tid == 0) s_nz = 0;
        __syncthreads();
        if (eisrc[2 * tid + 1] != 0u) atomicAdd(&s_nz, 1);
        __syncthreads();
        bool is64 = (s_nz == 0);
        long long i = (long long)(b - 770 - nzero) * 256 + tid;
        long long st = (long long)2000 * 256;
        if (is64) { for (; i < twoE; i += st) ei32[i] = (int)eisrc[2 * i]; }
        else      { for (; i < twoE; i += st) ei32[i] = (int)eisrc[i]; }
        return;
    }
    // LN1: one wave per 128-elem row
    int row = (b - 770 - nzero - 2000) * 4 + (tid >> 6);
    if (row >= N) return;
    int lane = tid & 63;
    float2 f = ((const float2*)x)[(size_t)row * 64 + lane];
    float s = f.x + f.y;
    #pragma unroll
    for (int off = 32; off > 0; off >>= 1) s += __shfl_xor(s, off);
    float mean = s * (1.0f / 128.0f);
    float d0 = f.x - mean, d1 = f.y - mean;
    float vs = d0 * d0 + d1 * d1;
    #pragma unroll
    for (int off = 32; off > 0; off >>= 1) vs += __shfl_xor(vs, off);
    float rstd = rsqrtf(vs * (1.0f / 128.0f) + 1e-5f);
    float2 gg = ((const float2*)g1)[lane];
    float2 bb = ((const float2*)b1)[lane];
    float o0 = d0 * rstd * gg.x + bb.x;
    float o1 = d1 * rstd * gg.y + bb.y;
    unsigned pk = ((unsigned)f2bf_bits(o1) << 16) | (unsigned)f2bf_bits(o0);
    ((unsigned*)hb)[(size_t)row * 64 + lane] = pk;
}

// ---------- CSR build ----------
__global__ __launch_bounds__(256) void count_deg_k(const int* __restrict__ ei,
                                                   int* __restrict__ deg, int E) {
    int e = blockIdx.x * 256 + threadIdx.x;
    if (e < E) atomicAdd(&deg[ei[E + e]], 1);
}

#define SCAN_BLK 1024
__global__ __launch_bounds__(256) void scan1_k(const int* __restrict__ deg,
                                               int* __restrict__ off,
                                               int* __restrict__ bsum, int n) {
    __shared__ int s[256];
    int base = blockIdx.x * SCAN_BLK;
    int t = threadIdx.x;
    int v[4]; int sum = 0;
    #pragma unroll
    for (int j = 0; j < 4; j++) {
        int idx = base + t * 4 + j;
        v[j] = (idx < n) ? deg[idx] : 0;
        sum += v[j];
    }
    s[t] = sum; __syncthreads();
    for (int o = 1; o < 256; o <<= 1) {
        int add = (t >= o) ? s[t - o] : 0;
        __syncthreads();
        s[t] += add;
        __syncthreads();
    }
    int run = (t > 0) ? s[t - 1] : 0;
    if (t == 255) bsum[blockIdx.x] = s[255];
    #pragma unroll
    for (int j = 0; j < 4; j++) {
        int idx = base + t * 4 + j;
        if (idx < n) off[idx] = run;
        run += v[j];
    }
}

// scan3 with scan2 (block-sum exclusive prefix) recomputed inline per block
__global__ __launch_bounds__(256) void scan3_k(int* __restrict__ off,
                                               int* __restrict__ cursor,
                                               const int* __restrict__ bsum,
                                               int n, int nb) {
    __shared__ int sb[64];
    int t = threadIdx.x;
    if (t < 64) {
        int own = (t < nb) ? bsum[t] : 0;
        int v = own;
        #pragma unroll
        for (int o = 1; o < 64; o <<= 1) {
            int u = __shfl_up(v, o);
            if ((t & 63) >= o) v += u;
        }
        sb[t] = v - own;   // exclusive
    }
    __syncthreads();
    int i = blockIdx.x * 256 + t;
    if (i < n) {
        int o = off[i] + sb[i / SCAN_BLK];
        off[i] = o;
        cursor[i] = o;
    }
}

__global__ __launch_bounds__(256) void scatter_k(const int* __restrict__ ei,
                                                 int* __restrict__ cursor,
                                                 int* __restrict__ csr, int E) {
    int e = blockIdx.x * 256 + threadIdx.x;
    if (e >= E) return;
    int s = ei[e], d = ei[E + e];
    int pos = atomicAdd(&cursor[d], 1);
    csr[pos] = s;
}

// ---------- MFMA GEMM, pipelined double-buffered LDS (BK=32, 1 barrier/step) ----------
// C[m,n] = A[m,:] @ B[n,:] + bias[n] (+gelu / +res / +fused-LN2-out)
// A: bf16 [Mp][K] row-major. B: bf16 [N][K] (pre-transposed, single bf16).
// 256 thr = 4 waves (2x2); block tile BM x 128; wave tile (BM/2) x 64.
// Pipeline: stage(0); for kt: sync; stage(kt+1, buf^1); compute(kt, buf).
// LDS: 2 x (BM*64 + 8K) = 32KB @BM=128 (5 blk/CU), 24KB @BM=64 (6 blk/CU)
// vs 48KB/3 blk with the old hi/lo split. Swizzle: chunk ^ ((row>>1)&3) -> 2-way.
template <int EPI, bool OUTBF, int K, int BM, bool LNF>
__global__ __launch_bounds__(256) void mgemm_k(const bf16* __restrict__ A,
                                               const bf16* __restrict__ Bh,
                                               const float* __restrict__ bias,
                                               const float* __restrict__ res,
                                               void* __restrict__ outp,
                                               const float* __restrict__ lg,
                                               const float* __restrict__ lb,
                                               bf16* __restrict__ hbout,
                                               long long sub_off, int M,
                                               int ldo, int sub_shift) {
    constexpr int MF = BM / 32;                 // 16-row frags per wave in m
    constexpr int NK = K / 32;                  // K-steps
    constexpr int STEP = BM * 64 + 8192;        // A(BM x 64B) + B(8K)
    __shared__ __align__(16) char smem[2 * STEP];

    const int lane = threadIdx.x & 63;
    const int wid  = threadIdx.x >> 6;
    const int wr = wid >> 1, wc = wid & 1;
    const int lrow = lane & 15, lk = lane >> 4;  // lk 0..3 = 16B chunk in 64B row
    const int m0 = blockIdx.y * BM;
    const int mw0 = wr * (BM / 2);
    const int n0 = blockIdx.x * 128 + wc * 64;
    const int srow = lane >> 2;                  // staging: row within 16-row group
    const int schunk = (lane & 3) ^ ((srow >> 1) & 3);  // pre-swizzled source chunk

    const char* Ab  = (const char*)A  + (size_t)m0 * (K * 2);
    const char* Bhb = (const char*)Bh + (size_t)(blockIdx.x * 128) * (K * 2);

    f32x4 acc[MF][4];
    #pragma unroll
    for (int mf = 0; mf < MF; mf++)
        #pragma unroll
        for (int nf = 0; nf < 4; nf++) {
            f32x4 z = {0.f, 0.f, 0.f, 0.f};
            acc[mf][nf] = z;
        }

    auto stage = [&](int kt, int bufb) {
        const int kb = kt * 64;                  // byte offset into K
        char* sb = &smem[bufb];
        #pragma unroll
        for (int it = 0; it < BM / 64; it++) {   // A: 16 rows per instr
            int rg = wid * (BM / 4) + it * 16;
            gload_lds16(Ab + (size_t)(rg + srow) * (K * 2) + kb + schunk * 16,
                        sb + rg * 64);
        }
        #pragma unroll
        for (int it = 0; it < 2; it++) {         // B: 128 rows
            int rg = wid * 32 + it * 16;
            gload_lds16(Bhb + (size_t)(rg + srow) * (K * 2) + kb + schunk * 16,
                        sb + BM * 64 + rg * 64);
        }
    };

    auto compute = [&](int bufb) {
        const char* sb = &smem[bufb];
        s16x8 a[MF], bh[4];
        #pragma unroll
        for (int mf = 0; mf < MF; mf++) {
            int ra = mw0 + mf * 16 + lrow;
            a[mf] = *(const s16x8*)(sb + ra * 64 + ((lk ^ ((ra >> 1) & 3)) * 16));
        }
        #pragma unroll
        for (int nf = 0; nf < 4; nf++) {
            int rb = wc * 64 + nf * 16 + lrow;
            int co = (lk ^ ((rb >> 1) & 3)) * 16;
            bh[nf] = *(const s16x8*)(sb + BM * 64 + rb * 64 + co);
        }
        #pragma unroll
        for (int mf = 0; mf < MF; mf++)
            #pragma unroll
            for (int nf = 0; nf < 4; nf++)
                acc[mf][nf] = __builtin_amdgcn_mfma_f32_16x16x32_bf16(a[mf], bh[nf], acc[mf][nf], 0, 0, 0);
    };

    stage(0, 0);
    for (int kt = 0; kt < NK; kt++) {
        __syncthreads();                         // buf[kt] staged; WAR-safe for next stage
        if (kt + 1 < NK) stage(kt + 1, ((kt + 1) & 1) * STEP);
        compute((kt & 1) * STEP);
    }

    if (!LNF) {
        const int nmask = (1 << sub_shift) - 1;
        #pragma unroll
        for (int mf = 0; mf < MF; mf++) {
            #pragma unroll
            for (int nf = 0; nf < 4; nf++) {
                int n = n0 + nf * 16 + lrow;
                float bsv = bias[n];
                #pragma unroll
                for (int r = 0; r < 4; r++) {
                    int m = m0 + mw0 + mf * 16 + lk * 4 + r;
                    if (m >= M) continue;
                    float val = acc[mf][nf][r] + bsv;
                    if (EPI == 1) val = 0.5f * val * (1.0f + erff(val * 0.70710678118f));
                    if (EPI == 2) val += res[(size_t)m * ldo + n];
                    long long oidx = (long long)m * ldo + (n & nmask) + (long long)(n >> sub_shift) * sub_off;
                    if (OUTBF) ((unsigned short*)outp)[oidx] = f2bf_bits(val);
                    else       ((float*)outp)[oidx] = val;
                }
            }
        }
    } else {
        // fused epilogue: out = acc + bias + res (fp32), then LN(out) -> bf16 hbout.
        // BM==64, ldo==128, gx==1: block owns full rows; cross-wave reduce via LDS.
        float vals[MF][4][4];
        float s1[MF][4], s2[MF][4];
        #pragma unroll
        for (int mf = 0; mf < MF; mf++)
            #pragma unroll
            for (int r = 0; r < 4; r++) { s1[mf][r] = 0.f; s2[mf][r] = 0.f; }
        #pragma unroll
        for (int mf = 0; mf < MF; mf++) {
            #pragma unroll
            for (int r = 0; r < 4; r++) {
                int m = m0 + mw0 + mf * 16 + lk * 4 + r;
                #pragma unroll
                for (int nf = 0; nf < 4; nf++) {
                    int n = n0 + nf * 16 + lrow;
                    float val = acc[mf][nf][r] + bias[n];
                    val += (m < M) ? res[(size_t)m * 128 + n] : 0.f;
                    vals[mf][nf][r] = val;
                    s1[mf][r] += val;
                    s2[mf][r] += val * val;
                }
                #pragma unroll
                for (int o = 1; o < 16; o <<= 1) {
                    s1[mf][r] += __shfl_xor(s1[mf][r], o);
                    s2[mf][r] += __shfl_xor(s2[mf][r], o);
                }
            }
        }
        float2* lns = (float2*)smem;             // [64 rows][2 col-halves]
        __syncthreads();                         // compute LDS reads done -> reuse
        if (lrow == 0) {
            #pragma unroll
            for (int mf = 0; mf < MF; mf++)
                #pragma unroll
                for (int r = 0; r < 4; r++) {
                    int rl = mw0 + mf * 16 + lk * 4 + r;
                    float2 p; p.x = s1[mf][r]; p.y = s2[mf][r];
                    lns[rl * 2 + wc] = p;
                }
        }
        __syncthreads();
        #pragma unroll
        for (int mf = 0; mf < MF; mf++) {
            #pragma unroll
            for (int r = 0; r < 4; r++) {
                int rl = mw0 + mf * 16 + lk * 4 + r;
                int m = m0 + rl;
                float2 pa = lns[rl * 2 + 0], pb = lns[rl * 2 + 1];
                float mean = (pa.x + pb.x) * (1.0f / 128.0f);
                float var  = (pa.y + pb.y) * (1.0f / 128.0f) - mean * mean;
                float rstd = rsqrtf(var + 1e-5f);
                if (m >= M) continue;
                #pragma unroll
                for (int nf = 0; nf < 4; nf++) {
                    int n = n0 + nf * 16 + lrow;
                    float val = vals[mf][nf][r];
                    ((float*)outp)[(size_t)m * 128 + n] = val;
                    float o = (val - mean) * rstd * lg[n] + lb[n];
                    ((unsigned short*)hbout)[(size_t)m * 128 + n] = f2bf_bits(o);
                }
            }
        }
    }
}

// ---------- node aggregation: one wave per dst node, CSR gather, no atomics ----------
// R5-measured-fast body: x8 unroll (16 gathers in flight), __expf, unscaled q.
__global__ __launch_bounds__(256) void node_agg_k(const bf16* __restrict__ q,
                                                  const bf16* __restrict__ k,
                                                  const bf16* __restrict__ v,
                                                  const int* __restrict__ off,
                                                  const int* __restrict__ deg,
                                                  const int* __restrict__ csr,
                                                  bf16* __restrict__ agg, int NN) {
    int node = blockIdx.x * 4 + (threadIdx.x >> 6);
    if (node >= NN) return;
    int lane = threadIdx.x & 63;
    float2 qf = bfpair(((const unsigned*)(q + (size_t)node * 128))[lane]);
    int start = off[node];
    int cnt = deg[node];
    float acc0 = 0.f, acc1 = 0.f, zsum = 0.f;
    if (cnt < 64) {
        int T = cnt + 1;                                  // + self-loop
        int s_vec = (lane < cnt) ? csr[start + lane] : node;
        for (int e0 = 0; e0 < T; e0 += 8) {
            unsigned ku[8], vu[8];
            #pragma unroll
            for (int j = 0; j < 8; j++) {
                if (e0 + j < T) {
                    int s = __shfl(s_vec, e0 + j);
                    ku[j] = ((const unsigned*)(k + (size_t)s * 128))[lane];
                    vu[j] = ((const unsigned*)(v + (size_t)s * 128))[lane];
                }
            }
            #pragma unroll
            for (int j = 0; j < 8; j++) {
                if (e0 + j < T) {
                    float2 kf = bfpair(ku[j]);
                    float dot = qf.x * kf.x + qf.y * kf.y;
                    dot += __shfl_xor(dot, 1);
                    dot += __shfl_xor(dot, 2);
                    dot += __shfl_xor(dot, 4);            // 8-lane (one head) reduce
                    float p = __expf(dot * 0.25f);
                    zsum += p;
                    float2 vf = bfpair(vu[j]);
                    acc0 += p * vf.x;
                    acc1 += p * vf.y;
                }
            }
        }
    } else {
        for (int e = 0; e <= cnt; e++) {
            int s = (e < cnt) ? csr[start + e] : node;
            float2 kf = bfpair(((const unsigned*)(k + (size_t)s * 128))[lane]);
            float dot = qf.x * kf.x + qf.y * kf.y;
            dot += __shfl_xor(dot, 1);
            dot += __shfl_xor(dot, 2);
            dot += __shfl_xor(dot, 4);
            float p = __expf(dot * 0.25f);
            zsum += p;
            float2 vf = bfpair(((const unsigned*)(v + (size_t)s * 128))[lane]);
            acc0 += p * vf.x;
            acc1 += p * vf.y;
        }
    }
    float2 o;
    if (cnt == 0) { o.x = 0.f; o.y = 0.f; }
    else { float inv = 1.0f / zsum; o.x = acc0 * inv; o.y = acc1 * inv; }
    unsigned pk = ((unsigned)f2bf_bits(o.y) << 16) | (unsigned)f2bf_bits(o.x);
    ((unsigned*)agg)[(size_t)node * 64 + lane] = pk;
}

// ---------- launch ----------
extern "C" void kernel_launch(void* const* d_in, const int* in_sizes, int n_in,
                              void* d_out, int out_size, void* d_ws, size_t ws_size,
                              hipStream_t stream) {
    const float* x  = (const float*)d_in[0];   // fp32, C-order [N,128]
    const void*  eiRaw = d_in[1];
    const float* Wq = (const float*)d_in[2];
    const float* bq = (const float*)d_in[3];
    const float* Wk = (const float*)d_in[4];
    const float* bk = (const float*)d_in[5];
    const float* Wv = (const float*)d_in[6];
    const float* bv = (const float*)d_in[7];
    const float* Wo = (const float*)d_in[8];
    const float* bo = (const float*)d_in[9];
    const float* g1 = (const float*)d_in[10];
    const float* b1 = (const float*)d_in[11];
    const float* g2 = (const float*)d_in[12];
    const float* b2 = (const float*)d_in[13];
    const float* W1 = (const float*)d_in[14];
    const float* bf1 = (const float*)d_in[15];
    const float* W2 = (const float*)d_in[16];
    const float* bf2 = (const float*)d_in[17];
    float* out = (float*)d_out;   // fp32 output; also holds x1

    const int N = in_sizes[0] / 128;
    const int E = in_sizes[1] / 2;
    const int gy = (N + 127) / 128;
    const int gy64 = (N + 63) / 64;
    const int Mp = gy * 128;      // padded row count for GEMM A-operands

    char* w = (char*)d_ws;
    size_t off_b = 0;
    auto alloc = [&](size_t bytes) -> void* {
        void* ptr = w + off_b;
        off_b = (off_b + bytes + 255) & ~(size_t)255;
        return ptr;
    };
    int*   deg    = (int*)alloc((size_t)N * 4);
    int*   offA   = (int*)alloc((size_t)N * 4);
    int*   cursor = (int*)alloc((size_t)N * 4);
    int*   bsum   = (int*)alloc(64 * 4);
    int*   ei32   = (int*)alloc((size_t)E * 2 * 4);
    int*   csr    = (int*)alloc((size_t)E * 4);
    bf16*  hb     = (bf16*)alloc((size_t)Mp * 128 * 2);   // LN1 out; reused for LN2 out
    bf16*  qkvb   = (bf16*)alloc((size_t)N * 3 * 128 * 2);
    bf16*  aggb   = (bf16*)alloc((size_t)Mp * 128 * 2);
    bf16*  t      = (bf16*)alloc((size_t)Mp * 512 * 2);
    unsigned short* qkvH = (unsigned short*)alloc(49152 * 2);
    unsigned short* woH  = (unsigned short*)alloc(16384 * 2);
    unsigned short* w1H  = (unsigned short*)alloc(65536 * 2);
    unsigned short* w2H  = (unsigned short*)alloc(65536 * 2);
    float* bqkv = (float*)alloc(384 * 4);
    (void)ws_size; (void)n_in; (void)out_size;

    int nb = (N + SCAN_BLK - 1) / SCAN_BLK;
    int nzero = (N + 255) / 256;
    int lnb = (N + 3) / 4;

    // fused setup: weight prep | zero deg | canon edge_index | LN1
    setup_k<<<770 + nzero + 2000 + lnb, 256, 0, stream>>>(
        Wq, Wk, Wv, Wo, W1, W2, bq, bk, bv,
        qkvH, woH, w1H, w2H, bqkv,
        deg, (const unsigned*)eiRaw, ei32, x, g1, b1, hb, N, E * 2, nzero);
    // CSR build
    count_deg_k<<<(E + 255) / 256, 256, 0, stream>>>(ei32, deg, E);
    scan1_k<<<nb, 256, 0, stream>>>(deg, offA, bsum, N);
    scan3_k<<<(N + 255) / 256, 256, 0, stream>>>(offA, cursor, bsum, N, nb);
    scatter_k<<<(E + 255) / 256, 256, 0, stream>>>(ei32, cursor, csr, E);

    bf16* qb = qkvb;
    bf16* kb = qkvb + (size_t)N * 128;
    bf16* vb = qkvb + (size_t)N * 256;

    // 1. fused QKV GEMM: [q|k|v] = hb @ Wqkv + bqkv (bf16 out, split by n>>7)
    mgemm_k<0, true, 128, 128, false><<<dim3(3, gy), 256, 0, stream>>>(
        hb, (const bf16*)qkvH, bqkv, nullptr, qkvb,
        nullptr, nullptr, nullptr, (long long)N * 128, N, 128, 7);
    // 2. segment softmax + aggregation (bf16 out)
    node_agg_k<<<(N + 3) / 4, 256, 0, stream>>>(qb, kb, vb, offA, deg, csr, aggb, N);
    // 3. x1 = x + aggb @ Wo + bo -> out (fp32), fused LN2 -> hb (bf16)
    mgemm_k<2, false, 128, 64, true><<<dim3(1, gy64), 256, 0, stream>>>(
        aggb, (const bf16*)woH, bo, x, out,
        g2, b2, hb, 0, N, 128, 15);
    // 4. t = gelu(hb @ W1 + bf1) (bf16)
    mgemm_k<1, true, 128, 128, false><<<dim3(4, gy), 256, 0, stream>>>(
        hb, (const bf16*)w1H, bf1, nullptr, t,
        nullptr, nullptr, nullptr, 0, N, 512, 15);
    // 5. out = x1 + t @ W2 + bf2 (fp32; res aliases out elementwise — safe)
    mgemm_k<2, false, 512, 64, false><<<dim3(1, gy64), 256, 0, stream>>>(
        t, (const bf16*)w2H, bf2, out, out,
        nullptr, nullptr, nullptr, 0, N, 128, 15);
}

// Round 15
// 383.324 us; speedup vs baseline: 1.2118x; 1.0162x over previous
//
#include <hip/hip_runtime.h>
#include <hip/hip_bf16.h>

typedef __hip_bfloat16 bf16;
typedef __attribute__((ext_vector_type(8))) short s16x8;
typedef __attribute__((ext_vector_type(4))) float f32x4;

// ---------- helpers ----------
__device__ __forceinline__ float2 bfpair(unsigned u) {
    float2 r;
    r.x = __uint_as_float(u << 16);
    r.y = __uint_as_float(u & 0xffff0000u);
    return r;
}

__device__ __forceinline__ unsigned short f2bf_bits(float f) {
    unsigned u = __float_as_uint(f);
    return (unsigned short)((u + 0x7fffu + ((u >> 16) & 1u)) >> 16);
}

// async global->LDS, 16B per lane; LDS dest wave-uniform base (lane*16 implicit)
typedef const __attribute__((address_space(1))) unsigned GU;
typedef __attribute__((address_space(3))) unsigned LU;
__device__ __forceinline__ void gload_lds16(const void* g, void* l) {
    __builtin_amdgcn_global_load_lds((GU*)g, (LU*)l, 16, 0, 0);
}

// ---------- fused setup: prepw (+bias pack) | zero deg | canon ei | LN1 ----------
// block ranges: [0,770) prepw; [770,+nzero) zero deg; [.., +2000) canon; rest LN1
__global__ __launch_bounds__(256) void setup_k(const float* __restrict__ Wq,
                                               const float* __restrict__ Wk,
                                               const float* __restrict__ Wv,
                                               const float* __restrict__ Wo,
                                               const float* __restrict__ W1,
                                               const float* __restrict__ W2,
                                               const float* __restrict__ bq,
                                               const float* __restrict__ bk,
                                               const float* __restrict__ bv,
                                               unsigned short* __restrict__ qkvH,
                                               unsigned short* __restrict__ woH,
                                               unsigned short* __restrict__ w1H,
                                               unsigned short* __restrict__ w2H,
                                               float* __restrict__ bqkv,
                                               int* __restrict__ deg,
                                               const unsigned* __restrict__ eisrc,
                                               int* __restrict__ ei32,
                                               const float* __restrict__ x,
                                               const float* __restrict__ g1,
                                               const float* __restrict__ b1,
                                               bf16* __restrict__ hb,
                                               int N, int twoE, int nzero) {
    int b = blockIdx.x;
    int tid = threadIdx.x;
    if (b < 770) {
        int idx = b * 256 + tid;
        if (idx >= 196608) {
            int i = idx - 196608;
            if (i < 384) bqkv[i] = (i < 128) ? bq[i] : (i < 256) ? bk[i - 128] : bv[i - 256];
            return;
        }
        float w; unsigned short *H; int oi;
        if (idx < 49152) {
            int n = idx >> 7, kx = idx & 127;
            const float* W = (n < 128) ? Wq : (n < 256) ? Wk : Wv;
            w = W[kx * 128 + (n & 127)];
            H = qkvH; oi = idx;
        } else if (idx < 65536) {
            int li = idx - 49152; int n = li >> 7, kx = li & 127;
            w = Wo[kx * 128 + n]; H = woH; oi = li;
        } else if (idx < 131072) {
            int li = idx - 65536; int n = li >> 7, kx = li & 127;
            w = W1[(size_t)kx * 512 + n]; H = w1H; oi = li;
        } else {
            int li = idx - 131072; int n = li >> 9, kx = li & 511;
            w = W2[(size_t)kx * 128 + n]; H = w2H; oi = li;
        }
        H[oi] = f2bf_bits(w);
        return;
    }
    if (b < 770 + nzero) {
        int i = (b - 770) * 256 + tid;
        if (i < N) deg[i] = 0;
        return;
    }
    if (b < 770 + nzero + 2000) {
        // canon: detect int64 vs int32 (parallel), convert to int32
        __shared__ int s_nz;
        if (tid == 0) s_nz = 0;
        __syncthreads();
        if (eisrc[2 * tid + 1] != 0u) atomicAdd(&s_nz, 1);
        __syncthreads();
        bool is64 = (s_nz == 0);
        long long i = (long long)(b - 770 - nzero) * 256 + tid;
        long long st = (long long)2000 * 256;
        if (is64) { for (; i < twoE; i += st) ei32[i] = (int)eisrc[2 * i]; }
        else      { for (; i < twoE; i += st) ei32[i] = (int)eisrc[i]; }
        return;
    }
    // LN1: one wave per 128-elem row
    int row = (b - 770 - nzero - 2000) * 4 + (tid >> 6);
    if (row >= N) return;
    int lane = tid & 63;
    float2 f = ((const float2*)x)[(size_t)row * 64 + lane];
    float s = f.x + f.y;
    #pragma unroll
    for (int off = 32; off > 0; off >>= 1) s += __shfl_xor(s, off);
    float mean = s * (1.0f / 128.0f);
    float d0 = f.x - mean, d1 = f.y - mean;
    float vs = d0 * d0 + d1 * d1;
    #pragma unroll
    for (int off = 32; off > 0; off >>= 1) vs += __shfl_xor(vs, off);
    float rstd = rsqrtf(vs * (1.0f / 128.0f) + 1e-5f);
    float2 gg = ((const float2*)g1)[lane];
    float2 bb = ((const float2*)b1)[lane];
    float o0 = d0 * rstd * gg.x + bb.x;
    float o1 = d1 * rstd * gg.y + bb.y;
    unsigned pk = ((unsigned)f2bf_bits(o1) << 16) | (unsigned)f2bf_bits(o0);
    ((unsigned*)hb)[(size_t)row * 64 + lane] = pk;
}

// ---------- CSR build ----------
__global__ __launch_bounds__(256) void count_deg_k(const int* __restrict__ ei,
                                                   int* __restrict__ deg, int E) {
    int e = blockIdx.x * 256 + threadIdx.x;
    if (e < E) atomicAdd(&deg[ei[E + e]], 1);
}

#define SCAN_BLK 1024
__global__ __launch_bounds__(256) void scan1_k(const int* __restrict__ deg,
                                               int* __restrict__ off,
                                               int* __restrict__ bsum, int n) {
    __shared__ int s[256];
    int base = blockIdx.x * SCAN_BLK;
    int t = threadIdx.x;
    int v[4]; int sum = 0;
    #pragma unroll
    for (int j = 0; j < 4; j++) {
        int idx = base + t * 4 + j;
        v[j] = (idx < n) ? deg[idx] : 0;
        sum += v[j];
    }
    s[t] = sum; __syncthreads();
    for (int o = 1; o < 256; o <<= 1) {
        int add = (t >= o) ? s[t - o] : 0;
        __syncthreads();
        s[t] += add;
        __syncthreads();
    }
    int run = (t > 0) ? s[t - 1] : 0;
    if (t == 255) bsum[blockIdx.x] = s[255];
    #pragma unroll
    for (int j = 0; j < 4; j++) {
        int idx = base + t * 4 + j;
        if (idx < n) off[idx] = run;
        run += v[j];
    }
}

// scan3 with scan2 (block-sum exclusive prefix) recomputed inline per block
__global__ __launch_bounds__(256) void scan3_k(int* __restrict__ off,
                                               int* __restrict__ cursor,
                                               const int* __restrict__ bsum,
                                               int n, int nb) {
    __shared__ int sb[64];
    int t = threadIdx.x;
    if (t < 64) {
        int own = (t < nb) ? bsum[t] : 0;
        int v = own;
        #pragma unroll
        for (int o = 1; o < 64; o <<= 1) {
            int u = __shfl_up(v, o);
            if ((t & 63) >= o) v += u;
        }
        sb[t] = v - own;   // exclusive
    }
    __syncthreads();
    int i = blockIdx.x * 256 + t;
    if (i < n) {
        int o = off[i] + sb[i / SCAN_BLK];
        off[i] = o;
        cursor[i] = o;
    }
}

__global__ __launch_bounds__(256) void scatter_k(const int* __restrict__ ei,
                                                 int* __restrict__ cursor,
                                                 int* __restrict__ csr, int E) {
    int e = blockIdx.x * 256 + threadIdx.x;
    if (e >= E) return;
    int s = ei[e], d = ei[E + e];
    int pos = atomicAdd(&cursor[d], 1);
    csr[pos] = s;
}

// ---------- MFMA GEMM, pipelined double-buffered LDS (BK=32, 1 barrier/step) ----------
// C[m,n] = A[m,:] @ B[n,:] + bias[n] (+gelu / +res / +fused-LN2-out)
// A: bf16 [Mp][K] row-major. B: bf16 [N][K] (pre-transposed, single bf16).
// 256 thr = 4 waves (2x2); block tile BM x 128; wave tile (BM/2) x 64.
// XCD swizzle (T1, bijective m204): HW round-robins linear wgid across 8 XCDs;
// remap so each XCD gets a CONTIGUOUS tile chunk -> gx-siblings sharing an A
// row-tile land on the same XCD L2 (was: A tile refetched into gx different L2s).
template <int EPI, bool OUTBF, int K, int BM, bool LNF>
__global__ __launch_bounds__(256) void mgemm_k(const bf16* __restrict__ A,
                                               const bf16* __restrict__ Bh,
                                               const float* __restrict__ bias,
                                               const float* __restrict__ res,
                                               void* __restrict__ outp,
                                               const float* __restrict__ lg,
                                               const float* __restrict__ lb,
                                               bf16* __restrict__ hbout,
                                               long long sub_off, int M,
                                               int ldo, int sub_shift) {
    constexpr int MF = BM / 32;                 // 16-row frags per wave in m
    constexpr int NK = K / 32;                  // K-steps
    constexpr int STEP = BM * 64 + 8192;        // A(BM x 64B) + B(8K)
    __shared__ __align__(16) char smem[2 * STEP];

    // ---- XCD-aware bijective block remap (m204) ----
    const int nwg = gridDim.x * gridDim.y;
    const int orig = blockIdx.y * gridDim.x + blockIdx.x;
    const int qq = nwg >> 3, rr = nwg & 7;
    const int xcd = orig & 7, jj = orig >> 3;
    const int tile = ((xcd < rr) ? xcd * (qq + 1) : rr * (qq + 1) + (xcd - rr) * qq) + jj;
    const int bx = tile % gridDim.x;
    const int by = tile / gridDim.x;

    const int lane = threadIdx.x & 63;
    const int wid  = threadIdx.x >> 6;
    const int wr = wid >> 1, wc = wid & 1;
    const int lrow = lane & 15, lk = lane >> 4;  // lk 0..3 = 16B chunk in 64B row
    const int m0 = by * BM;
    const int mw0 = wr * (BM / 2);
    const int n0 = bx * 128 + wc * 64;
    const int srow = lane >> 2;                  // staging: row within 16-row group
    const int schunk = (lane & 3) ^ ((srow >> 1) & 3);  // pre-swizzled source chunk

    const char* Ab  = (const char*)A  + (size_t)m0 * (K * 2);
    const char* Bhb = (const char*)Bh + (size_t)(bx * 128) * (K * 2);

    f32x4 acc[MF][4];
    #pragma unroll
    for (int mf = 0; mf < MF; mf++)
        #pragma unroll
        for (int nf = 0; nf < 4; nf++) {
            f32x4 z = {0.f, 0.f, 0.f, 0.f};
            acc[mf][nf] = z;
        }

    auto stage = [&](int kt, int bufb) {
        const int kb = kt * 64;                  // byte offset into K
        char* sb = &smem[bufb];
        #pragma unroll
        for (int it = 0; it < BM / 64; it++) {   // A: 16 rows per instr
            int rg = wid * (BM / 4) + it * 16;
            gload_lds16(Ab + (size_t)(rg + srow) * (K * 2) + kb + schunk * 16,
                        sb + rg * 64);
        }
        #pragma unroll
        for (int it = 0; it < 2; it++) {         // B: 128 rows
            int rg = wid * 32 + it * 16;
            gload_lds16(Bhb + (size_t)(rg + srow) * (K * 2) + kb + schunk * 16,
                        sb + BM * 64 + rg * 64);
        }
    };

    auto compute = [&](int bufb) {
        const char* sb = &smem[bufb];
        s16x8 a[MF], bh[4];
        #pragma unroll
        for (int mf = 0; mf < MF; mf++) {
            int ra = mw0 + mf * 16 + lrow;
            a[mf] = *(const s16x8*)(sb + ra * 64 + ((lk ^ ((ra >> 1) & 3)) * 16));
        }
        #pragma unroll
        for (int nf = 0; nf < 4; nf++) {
            int rb = wc * 64 + nf * 16 + lrow;
            int co = (lk ^ ((rb >> 1) & 3)) * 16;
            bh[nf] = *(const s16x8*)(sb + BM * 64 + rb * 64 + co);
        }
        #pragma unroll
        for (int mf = 0; mf < MF; mf++)
            #pragma unroll
            for (int nf = 0; nf < 4; nf++)
                acc[mf][nf] = __builtin_amdgcn_mfma_f32_16x16x32_bf16(a[mf], bh[nf], acc[mf][nf], 0, 0, 0);
    };

    stage(0, 0);
    for (int kt = 0; kt < NK; kt++) {
        __syncthreads();                         // buf[kt] staged; WAR-safe for next stage
        if (kt + 1 < NK) stage(kt + 1, ((kt + 1) & 1) * STEP);
        compute((kt & 1) * STEP);
    }

    if (!LNF) {
        const int nmask = (1 << sub_shift) - 1;
        #pragma unroll
        for (int mf = 0; mf < MF; mf++) {
            #pragma unroll
            for (int nf = 0; nf < 4; nf++) {
                int n = n0 + nf * 16 + lrow;
                float bsv = bias[n];
                #pragma unroll
                for (int r = 0; r < 4; r++) {
                    int m = m0 + mw0 + mf * 16 + lk * 4 + r;
                    if (m >= M) continue;
                    float val = acc[mf][nf][r] + bsv;
                    if (EPI == 1) val = 0.5f * val * (1.0f + erff(val * 0.70710678118f));
                    if (EPI == 2) val += res[(size_t)m * ldo + n];
                    long long oidx = (long long)m * ldo + (n & nmask) + (long long)(n >> sub_shift) * sub_off;
                    if (OUTBF) ((unsigned short*)outp)[oidx] = f2bf_bits(val);
                    else       ((float*)outp)[oidx] = val;
                }
            }
        }
    } else {
        // fused epilogue: out = acc + bias + res (fp32), then LN(out) -> bf16 hbout.
        // BM==64, ldo==128, gx==1: block owns full rows; cross-wave reduce via LDS.
        float vals[MF][4][4];
        float s1[MF][4], s2[MF][4];
        #pragma unroll
        for (int mf = 0; mf < MF; mf++)
            #pragma unroll
            for (int r = 0; r < 4; r++) { s1[mf][r] = 0.f; s2[mf][r] = 0.f; }
        #pragma unroll
        for (int mf = 0; mf < MF; mf++) {
            #pragma unroll
            for (int r = 0; r < 4; r++) {
                int m = m0 + mw0 + mf * 16 + lk * 4 + r;
                #pragma unroll
                for (int nf = 0; nf < 4; nf++) {
                    int n = n0 + nf * 16 + lrow;
                    float val = acc[mf][nf][r] + bias[n];
                    val += (m < M) ? res[(size_t)m * 128 + n] : 0.f;
                    vals[mf][nf][r] = val;
                    s1[mf][r] += val;
                    s2[mf][r] += val * val;
                }
                #pragma unroll
                for (int o = 1; o < 16; o <<= 1) {
                    s1[mf][r] += __shfl_xor(s1[mf][r], o);
                    s2[mf][r] += __shfl_xor(s2[mf][r], o);
                }
            }
        }
        float2* lns = (float2*)smem;             // [64 rows][2 col-halves]
        __syncthreads();                         // compute LDS reads done -> reuse
        if (lrow == 0) {
            #pragma unroll
            for (int mf = 0; mf < MF; mf++)
                #pragma unroll
                for (int r = 0; r < 4; r++) {
                    int rl = mw0 + mf * 16 + lk * 4 + r;
                    float2 p; p.x = s1[mf][r]; p.y = s2[mf][r];
                    lns[rl * 2 + wc] = p;
                }
        }
        __syncthreads();
        #pragma unroll
        for (int mf = 0; mf < MF; mf++) {
            #pragma unroll
            for (int r = 0; r < 4; r++) {
                int rl = mw0 + mf * 16 + lk * 4 + r;
                int m = m0 + rl;
                float2 pa = lns[rl * 2 + 0], pb = lns[rl * 2 + 1];
                float mean = (pa.x + pb.x) * (1.0f / 128.0f);
                float var  = (pa.y + pb.y) * (1.0f / 128.0f) - mean * mean;
                float rstd = rsqrtf(var + 1e-5f);
                if (m >= M) continue;
                #pragma unroll
                for (int nf = 0; nf < 4; nf++) {
                    int n = n0 + nf * 16 + lrow;
                    float val = vals[mf][nf][r];
                    ((float*)outp)[(size_t)m * 128 + n] = val;
                    float o = (val - mean) * rstd * lg[n] + lb[n];
                    ((unsigned short*)hbout)[(size_t)m * 128 + n] = f2bf_bits(o);
                }
            }
        }
    }
}

// ---------- node aggregation: one wave per dst node, CSR gather, no atomics ----------
// R5-measured-fast body: x8 unroll (16 gathers in flight), __expf, unscaled q.
__global__ __launch_bounds__(256) void node_agg_k(const bf16* __restrict__ q,
                                                  const bf16* __restrict__ k,
                                                  const bf16* __restrict__ v,
                                                  const int* __restrict__ off,
                                                  const int* __restrict__ deg,
                                                  const int* __restrict__ csr,
                                                  bf16* __restrict__ agg, int NN) {
    int node = blockIdx.x * 4 + (threadIdx.x >> 6);
    if (node >= NN) return;
    int lane = threadIdx.x & 63;
    float2 qf = bfpair(((const unsigned*)(q + (size_t)node * 128))[lane]);
    int start = off[node];
    int cnt = deg[node];
    float acc0 = 0.f, acc1 = 0.f, zsum = 0.f;
    if (cnt < 64) {
        int T = cnt + 1;                                  // + self-loop
        int s_vec = (lane < cnt) ? csr[start + lane] : node;
        for (int e0 = 0; e0 < T; e0 += 8) {
            unsigned ku[8], vu[8];
            #pragma unroll
            for (int j = 0; j < 8; j++) {
                if (e0 + j < T) {
                    int s = __shfl(s_vec, e0 + j);
                    ku[j] = ((const unsigned*)(k + (size_t)s * 128))[lane];
                    vu[j] = ((const unsigned*)(v + (size_t)s * 128))[lane];
                }
            }
            #pragma unroll
            for (int j = 0; j < 8; j++) {
                if (e0 + j < T) {
                    float2 kf = bfpair(ku[j]);
                    float dot = qf.x * kf.x + qf.y * kf.y;
                    dot += __shfl_xor(dot, 1);
                    dot += __shfl_xor(dot, 2);
                    dot += __shfl_xor(dot, 4);            // 8-lane (one head) reduce
                    float p = __expf(dot * 0.25f);
                    zsum += p;
                    float2 vf = bfpair(vu[j]);
                    acc0 += p * vf.x;
                    acc1 += p * vf.y;
                }
            }
        }
    } else {
        for (int e = 0; e <= cnt; e++) {
            int s = (e < cnt) ? csr[start + e] : node;
            float2 kf = bfpair(((const unsigned*)(k + (size_t)s * 128))[lane]);
            float dot = qf.x * kf.x + qf.y * kf.y;
            dot += __shfl_xor(dot, 1);
            dot += __shfl_xor(dot, 2);
            dot += __shfl_xor(dot, 4);
            float p = __expf(dot * 0.25f);
            zsum += p;
            float2 vf = bfpair(((const unsigned*)(v + (size_t)s * 128))[lane]);
            acc0 += p * vf.x;
            acc1 += p * vf.y;
        }
    }
    float2 o;
    if (cnt == 0) { o.x = 0.f; o.y = 0.f; }
    else { float inv = 1.0f / zsum; o.x = acc0 * inv; o.y = acc1 * inv; }
    unsigned pk = ((unsigned)f2bf_bits(o.y) << 16) | (unsigned)f2bf_bits(o.x);
    ((unsigned*)agg)[(size_t)node * 64 + lane] = pk;
}

// ---------- launch ----------
extern "C" void kernel_launch(void* const* d_in, const int* in_sizes, int n_in,
                              void* d_out, int out_size, void* d_ws, size_t ws_size,
                              hipStream_t stream) {
    const float* x  = (const float*)d_in[0];   // fp32, C-order [N,128]
    const void*  eiRaw = d_in[1];
    const float* Wq = (const float*)d_in[2];
    const float* bq = (const float*)d_in[3];
    const float* Wk = (const float*)d_in[4];
    const float* bk = (const float*)d_in[5];
    const float* Wv = (const float*)d_in[6];
    const float* bv = (const float*)d_in[7];
    const float* Wo = (const float*)d_in[8];
    const float* bo = (const float*)d_in[9];
    const float* g1 = (const float*)d_in[10];
    const float* b1 = (const float*)d_in[11];
    const float* g2 = (const float*)d_in[12];
    const float* b2 = (const float*)d_in[13];
    const float* W1 = (const float*)d_in[14];
    const float* bf1 = (const float*)d_in[15];
    const float* W2 = (const float*)d_in[16];
    const float* bf2 = (const float*)d_in[17];
    float* out = (float*)d_out;   // fp32 output; also holds x1

    const int N = in_sizes[0] / 128;
    const int E = in_sizes[1] / 2;
    const int gy = (N + 127) / 128;
    const int gy64 = (N + 63) / 64;
    const int Mp = gy * 128;      // padded row count for GEMM A-operands

    char* w = (char*)d_ws;
    size_t off_b = 0;
    auto alloc = [&](size_t bytes) -> void* {
        void* ptr = w + off_b;
        off_b = (off_b + bytes + 255) & ~(size_t)255;
        return ptr;
    };
    int*   deg    = (int*)alloc((size_t)N * 4);
    int*   offA   = (int*)alloc((size_t)N * 4);
    int*   cursor = (int*)alloc((size_t)N * 4);
    int*   bsum   = (int*)alloc(64 * 4);
    int*   ei32   = (int*)alloc((size_t)E * 2 * 4);
    int*   csr    = (int*)alloc((size_t)E * 4);
    bf16*  hb     = (bf16*)alloc((size_t)Mp * 128 * 2);   // LN1 out; reused for LN2 out
    bf16*  qkvb   = (bf16*)alloc((size_t)N * 3 * 128 * 2);
    bf16*  aggb   = (bf16*)alloc((size_t)Mp * 128 * 2);
    bf16*  t      = (bf16*)alloc((size_t)Mp * 512 * 2);
    unsigned short* qkvH = (unsigned short*)alloc(49152 * 2);
    unsigned short* woH  = (unsigned short*)alloc(16384 * 2);
    unsigned short* w1H  = (unsigned short*)alloc(65536 * 2);
    unsigned short* w2H  = (unsigned short*)alloc(65536 * 2);
    float* bqkv = (float*)alloc(384 * 4);
    (void)ws_size; (void)n_in; (void)out_size;

    int nb = (N + SCAN_BLK - 1) / SCAN_BLK;
    int nzero = (N + 255) / 256;
    int lnb = (N + 3) / 4;

    // fused setup: weight prep | zero deg | canon edge_index | LN1
    setup_k<<<770 + nzero + 2000 + lnb, 256, 0, stream>>>(
        Wq, Wk, Wv, Wo, W1, W2, bq, bk, bv,
        qkvH, woH, w1H, w2H, bqkv,
        deg, (const unsigned*)eiRaw, ei32, x, g1, b1, hb, N, E * 2, nzero);
    // CSR build
    count_deg_k<<<(E + 255) / 256, 256, 0, stream>>>(ei32, deg, E);
    scan1_k<<<nb, 256, 0, stream>>>(deg, offA, bsum, N);
    scan3_k<<<(N + 255) / 256, 256, 0, stream>>>(offA, cursor, bsum, N, nb);
    scatter_k<<<(E + 255) / 256, 256, 0, stream>>>(ei32, cursor, csr, E);

    bf16* qb = qkvb;
    bf16* kb = qkvb + (size_t)N * 128;
    bf16* vb = qkvb + (size_t)N * 256;

    // 1. fused QKV GEMM: [q|k|v] = hb @ Wqkv + bqkv (bf16 out, split by n>>7)
    mgemm_k<0, true, 128, 128, false><<<dim3(3, gy), 256, 0, stream>>>(
        hb, (const bf16*)qkvH, bqkv, nullptr, qkvb,
        nullptr, nullptr, nullptr, (long long)N * 128, N, 128, 7);
    // 2. segment softmax + aggregation (bf16 out)
    node_agg_k<<<(N + 3) / 4, 256, 0, stream>>>(qb, kb, vb, offA, deg, csr, aggb, N);
    // 3. x1 = x + aggb @ Wo + bo -> out (fp32), fused LN2 -> hb (bf16)
    mgemm_k<2, false, 128, 64, true><<<dim3(1, gy64), 256, 0, stream>>>(
        aggb, (const bf16*)woH, bo, x, out,
        g2, b2, hb, 0, N, 128, 15);
    // 4. t = gelu(hb @ W1 + bf1) (bf16)
    mgemm_k<1, true, 128, 128, false><<<dim3(4, gy), 256, 0, stream>>>(
        hb, (const bf16*)w1H, bf1, nullptr, t,
        nullptr, nullptr, nullptr, 0, N, 512, 15);
    // 5. out = x1 + t @ W2 + bf2 (fp32; res aliases out elementwise — safe)
    mgemm_k<2, false, 512, 64, false><<<dim3(1, gy64), 256, 0, stream>>>(
        t, (const bf16*)w2H, bf2, out, out,
        nullptr, nullptr, nullptr, 0, N, 128, 15);
}

// Round 16
// 369.980 us; speedup vs baseline: 1.2555x; 1.0361x over previous
//
#include <hip/hip_runtime.h>
#include <hip/hip_bf16.h>

typedef __hip_bfloat16 bf16;
typedef __attribute__((ext_vector_type(8))) short s16x8;
typedef __attribute__((ext_vector_type(4))) float f32x4;

// ---------- helpers ----------
__device__ __forceinline__ float2 bfpair(unsigned u) {
    float2 r;
    r.x = __uint_as_float(u << 16);
    r.y = __uint_as_float(u & 0xffff0000u);
    return r;
}

__device__ __forceinline__ unsigned short f2bf_bits(float f) {
    unsigned u = __float_as_uint(f);
    return (unsigned short)((u + 0x7fffu + ((u >> 16) & 1u)) >> 16);
}

// async global->LDS, 16B per lane; LDS dest wave-uniform base (lane*16 implicit)
typedef const __attribute__((address_space(1))) unsigned GU;
typedef __attribute__((address_space(3))) unsigned LU;
__device__ __forceinline__ void gload_lds16(const void* g, void* l) {
    __builtin_amdgcn_global_load_lds((GU*)g, (LU*)l, 16, 0, 0);
}

// ---------- fused setup: prepw (+bias pack) | zero deg | canon ei | LN1 ----------
__global__ __launch_bounds__(256) void setup_k(const float* __restrict__ Wq,
                                               const float* __restrict__ Wk,
                                               const float* __restrict__ Wv,
                                               const float* __restrict__ Wo,
                                               const float* __restrict__ W1,
                                               const float* __restrict__ W2,
                                               const float* __restrict__ bq,
                                               const float* __restrict__ bk,
                                               const float* __restrict__ bv,
                                               unsigned short* __restrict__ qkvH,
                                               unsigned short* __restrict__ woH,
                                               unsigned short* __restrict__ w1H,
                                               unsigned short* __restrict__ w2H,
                                               float* __restrict__ bqkv,
                                               int* __restrict__ deg,
                                               const unsigned* __restrict__ eisrc,
                                               int* __restrict__ ei32,
                                               const float* __restrict__ x,
                                               const float* __restrict__ g1,
                                               const float* __restrict__ b1,
                                               bf16* __restrict__ hb,
                                               int N, int twoE, int nzero) {
    int b = blockIdx.x;
    int tid = threadIdx.x;
    if (b < 770) {
        int idx = b * 256 + tid;
        if (idx >= 196608) {
            int i = idx - 196608;
            if (i < 384) bqkv[i] = (i < 128) ? bq[i] : (i < 256) ? bk[i - 128] : bv[i - 256];
            return;
        }
        float w; unsigned short *H; int oi;
        if (idx < 49152) {
            int n = idx >> 7, kx = idx & 127;
            const float* W = (n < 128) ? Wq : (n < 256) ? Wk : Wv;
            w = W[kx * 128 + (n & 127)];
            H = qkvH; oi = idx;
        } else if (idx < 65536) {
            int li = idx - 49152; int n = li >> 7, kx = li & 127;
            w = Wo[kx * 128 + n]; H = woH; oi = li;
        } else if (idx < 131072) {
            int li = idx - 65536; int n = li >> 7, kx = li & 127;
            w = W1[(size_t)kx * 512 + n]; H = w1H; oi = li;
        } else {
            int li = idx - 131072; int n = li >> 9, kx = li & 511;
            w = W2[(size_t)kx * 128 + n]; H = w2H; oi = li;
        }
        H[oi] = f2bf_bits(w);
        return;
    }
    if (b < 770 + nzero) {
        int i = (b - 770) * 256 + tid;
        if (i < N) deg[i] = 0;
        return;
    }
    if (b < 770 + nzero + 2000) {
        // canon: detect int64 vs int32 (parallel), convert to int32
        __shared__ int s_nz;
        if (tid == 0) s_nz = 0;
        __syncthreads();
        if (eisrc[2 * tid + 1] != 0u) atomicAdd(&s_nz, 1);
        __syncthreads();
        bool is64 = (s_nz == 0);
        long long i = (long long)(b - 770 - nzero) * 256 + tid;
        long long st = (long long)2000 * 256;
        if (is64) { for (; i < twoE; i += st) ei32[i] = (int)eisrc[2 * i]; }
        else      { for (; i < twoE; i += st) ei32[i] = (int)eisrc[i]; }
        return;
    }
    // LN1: one wave per 128-elem row
    int row = (b - 770 - nzero - 2000) * 4 + (tid >> 6);
    if (row >= N) return;
    int lane = tid & 63;
    float2 f = ((const float2*)x)[(size_t)row * 64 + lane];
    float s = f.x + f.y;
    #pragma unroll
    for (int off = 32; off > 0; off >>= 1) s += __shfl_xor(s, off);
    float mean = s * (1.0f / 128.0f);
    float d0 = f.x - mean, d1 = f.y - mean;
    float vs = d0 * d0 + d1 * d1;
    #pragma unroll
    for (int off = 32; off > 0; off >>= 1) vs += __shfl_xor(vs, off);
    float rstd = rsqrtf(vs * (1.0f / 128.0f) + 1e-5f);
    float2 gg = ((const float2*)g1)[lane];
    float2 bb = ((const float2*)b1)[lane];
    float o0 = d0 * rstd * gg.x + bb.x;
    float o1 = d1 * rstd * gg.y + bb.y;
    unsigned pk = ((unsigned)f2bf_bits(o1) << 16) | (unsigned)f2bf_bits(o0);
    ((unsigned*)hb)[(size_t)row * 64 + lane] = pk;
}

// ---------- CSR build ----------
__global__ __launch_bounds__(256) void count_deg_k(const int* __restrict__ ei,
                                                   int* __restrict__ deg, int E) {
    int e = blockIdx.x * 256 + threadIdx.x;
    if (e < E) atomicAdd(&deg[ei[E + e]], 1);
}

#define SCAN_BLK 1024
__global__ __launch_bounds__(256) void scan1_k(const int* __restrict__ deg,
                                               int* __restrict__ off,
                                               int* __restrict__ bsum, int n) {
    __shared__ int s[256];
    int base = blockIdx.x * SCAN_BLK;
    int t = threadIdx.x;
    int v[4]; int sum = 0;
    #pragma unroll
    for (int j = 0; j < 4; j++) {
        int idx = base + t * 4 + j;
        v[j] = (idx < n) ? deg[idx] : 0;
        sum += v[j];
    }
    s[t] = sum; __syncthreads();
    for (int o = 1; o < 256; o <<= 1) {
        int add = (t >= o) ? s[t - o] : 0;
        __syncthreads();
        s[t] += add;
        __syncthreads();
    }
    int run = (t > 0) ? s[t - 1] : 0;
    if (t == 255) bsum[blockIdx.x] = s[255];
    #pragma unroll
    for (int j = 0; j < 4; j++) {
        int idx = base + t * 4 + j;
        if (idx < n) off[idx] = run;
        run += v[j];
    }
}

// scan3 with scan2 (block-sum exclusive prefix) recomputed inline per block
__global__ __launch_bounds__(256) void scan3_k(int* __restrict__ off,
                                               int* __restrict__ cursor,
                                               const int* __restrict__ bsum,
                                               int n, int nb) {
    __shared__ int sb[64];
    int t = threadIdx.x;
    if (t < 64) {
        int own = (t < nb) ? bsum[t] : 0;
        int v = own;
        #pragma unroll
        for (int o = 1; o < 64; o <<= 1) {
            int u = __shfl_up(v, o);
            if ((t & 63) >= o) v += u;
        }
        sb[t] = v - own;   // exclusive
    }
    __syncthreads();
    int i = blockIdx.x * 256 + t;
    if (i < n) {
        int o = off[i] + sb[i / SCAN_BLK];
        off[i] = o;
        cursor[i] = o;
    }
}

__global__ __launch_bounds__(256) void scatter_k(const int* __restrict__ ei,
                                                 int* __restrict__ cursor,
                                                 int* __restrict__ csr, int E) {
    int e = blockIdx.x * 256 + threadIdx.x;
    if (e >= E) return;
    int s = ei[e], d = ei[E + e];
    int pos = atomicAdd(&cursor[d], 1);
    csr[pos] = s;
}

// ---------- MFMA GEMM, pipelined double-buffered LDS (BK=32, 1 barrier/step) ----------
// (unchanged R15 structure; used for QKV and Wo+LN2)
template <int EPI, bool OUTBF, int K, int BM, bool LNF>
__global__ __launch_bounds__(256) void mgemm_k(const bf16* __restrict__ A,
                                               const bf16* __restrict__ Bh,
                                               const float* __restrict__ bias,
                                               const float* __restrict__ res,
                                               void* __restrict__ outp,
                                               const float* __restrict__ lg,
                                               const float* __restrict__ lb,
                                               bf16* __restrict__ hbout,
                                               long long sub_off, int M,
                                               int ldo, int sub_shift) {
    constexpr int MF = BM / 32;                 // 16-row frags per wave in m
    constexpr int NK = K / 32;                  // K-steps
    constexpr int STEP = BM * 64 + 8192;        // A(BM x 64B) + B(8K)
    __shared__ __align__(16) char smem[2 * STEP];

    // ---- XCD-aware bijective block remap (m204) ----
    const int nwg = gridDim.x * gridDim.y;
    const int orig = blockIdx.y * gridDim.x + blockIdx.x;
    const int qq = nwg >> 3, rr = nwg & 7;
    const int xcd = orig & 7, jj = orig >> 3;
    const int tile = ((xcd < rr) ? xcd * (qq + 1) : rr * (qq + 1) + (xcd - rr) * qq) + jj;
    const int bx = tile % gridDim.x;
    const int by = tile / gridDim.x;

    const int lane = threadIdx.x & 63;
    const int wid  = threadIdx.x >> 6;
    const int wr = wid >> 1, wc = wid & 1;
    const int lrow = lane & 15, lk = lane >> 4;  // lk 0..3 = 16B chunk in 64B row
    const int m0 = by * BM;
    const int mw0 = wr * (BM / 2);
    const int n0 = bx * 128 + wc * 64;
    const int srow = lane >> 2;                  // staging: row within 16-row group
    const int schunk = (lane & 3) ^ ((srow >> 1) & 3);  // pre-swizzled source chunk

    const char* Ab  = (const char*)A  + (size_t)m0 * (K * 2);
    const char* Bhb = (const char*)Bh + (size_t)(bx * 128) * (K * 2);

    f32x4 acc[MF][4];
    #pragma unroll
    for (int mf = 0; mf < MF; mf++)
        #pragma unroll
        for (int nf = 0; nf < 4; nf++) {
            f32x4 z = {0.f, 0.f, 0.f, 0.f};
            acc[mf][nf] = z;
        }

    auto stage = [&](int kt, int bufb) {
        const int kb = kt * 64;                  // byte offset into K
        char* sb = &smem[bufb];
        #pragma unroll
        for (int it = 0; it < BM / 64; it++) {   // A: 16 rows per instr
            int rg = wid * (BM / 4) + it * 16;
            gload_lds16(Ab + (size_t)(rg + srow) * (K * 2) + kb + schunk * 16,
                        sb + rg * 64);
        }
        #pragma unroll
        for (int it = 0; it < 2; it++) {         // B: 128 rows
            int rg = wid * 32 + it * 16;
            gload_lds16(Bhb + (size_t)(rg + srow) * (K * 2) + kb + schunk * 16,
                        sb + BM * 64 + rg * 64);
        }
    };

    auto compute = [&](int bufb) {
        const char* sb = &smem[bufb];
        s16x8 a[MF], bh[4];
        #pragma unroll
        for (int mf = 0; mf < MF; mf++) {
            int ra = mw0 + mf * 16 + lrow;
            a[mf] = *(const s16x8*)(sb + ra * 64 + ((lk ^ ((ra >> 1) & 3)) * 16));
        }
        #pragma unroll
        for (int nf = 0; nf < 4; nf++) {
            int rb = wc * 64 + nf * 16 + lrow;
            int co = (lk ^ ((rb >> 1) & 3)) * 16;
            bh[nf] = *(const s16x8*)(sb + BM * 64 + rb * 64 + co);
        }
        #pragma unroll
        for (int mf = 0; mf < MF; mf++)
            #pragma unroll
            for (int nf = 0; nf < 4; nf++)
                acc[mf][nf] = __builtin_amdgcn_mfma_f32_16x16x32_bf16(a[mf], bh[nf], acc[mf][nf], 0, 0, 0);
    };

    stage(0, 0);
    for (int kt = 0; kt < NK; kt++) {
        __syncthreads();                         // buf[kt] staged; WAR-safe for next stage
        if (kt + 1 < NK) stage(kt + 1, ((kt + 1) & 1) * STEP);
        compute((kt & 1) * STEP);
    }

    if (!LNF) {
        const int nmask = (1 << sub_shift) - 1;
        #pragma unroll
        for (int mf = 0; mf < MF; mf++) {
            #pragma unroll
            for (int nf = 0; nf < 4; nf++) {
                int n = n0 + nf * 16 + lrow;
                float bsv = bias[n];
                #pragma unroll
                for (int r = 0; r < 4; r++) {
                    int m = m0 + mw0 + mf * 16 + lk * 4 + r;
                    if (m >= M) continue;
                    float val = acc[mf][nf][r] + bsv;
                    if (EPI == 1) val = 0.5f * val * (1.0f + erff(val * 0.70710678118f));
                    if (EPI == 2) val += res[(size_t)m * ldo + n];
                    long long oidx = (long long)m * ldo + (n & nmask) + (long long)(n >> sub_shift) * sub_off;
                    if (OUTBF) ((unsigned short*)outp)[oidx] = f2bf_bits(val);
                    else       ((float*)outp)[oidx] = val;
                }
            }
        }
    } else {
        // fused epilogue: out = acc + bias + res (fp32), then LN(out) -> bf16 hbout.
        float vals[MF][4][4];
        float s1[MF][4], s2[MF][4];
        #pragma unroll
        for (int mf = 0; mf < MF; mf++)
            #pragma unroll
            for (int r = 0; r < 4; r++) { s1[mf][r] = 0.f; s2[mf][r] = 0.f; }
        #pragma unroll
        for (int mf = 0; mf < MF; mf++) {
            #pragma unroll
            for (int r = 0; r < 4; r++) {
                int m = m0 + mw0 + mf * 16 + lk * 4 + r;
                #pragma unroll
                for (int nf = 0; nf < 4; nf++) {
                    int n = n0 + nf * 16 + lrow;
                    float val = acc[mf][nf][r] + bias[n];
                    val += (m < M) ? res[(size_t)m * 128 + n] : 0.f;
                    vals[mf][nf][r] = val;
                    s1[mf][r] += val;
                    s2[mf][r] += val * val;
                }
                #pragma unroll
                for (int o = 1; o < 16; o <<= 1) {
                    s1[mf][r] += __shfl_xor(s1[mf][r], o);
                    s2[mf][r] += __shfl_xor(s2[mf][r], o);
                }
            }
        }
        float2* lns = (float2*)smem;             // [64 rows][2 col-halves]
        __syncthreads();                         // compute LDS reads done -> reuse
        if (lrow == 0) {
            #pragma unroll
            for (int mf = 0; mf < MF; mf++)
                #pragma unroll
                for (int r = 0; r < 4; r++) {
                    int rl = mw0 + mf * 16 + lk * 4 + r;
                    float2 p; p.x = s1[mf][r]; p.y = s2[mf][r];
                    lns[rl * 2 + wc] = p;
                }
        }
        __syncthreads();
        #pragma unroll
        for (int mf = 0; mf < MF; mf++) {
            #pragma unroll
            for (int r = 0; r < 4; r++) {
                int rl = mw0 + mf * 16 + lk * 4 + r;
                int m = m0 + rl;
                float2 pa = lns[rl * 2 + 0], pb = lns[rl * 2 + 1];
                float mean = (pa.x + pb.x) * (1.0f / 128.0f);
                float var  = (pa.y + pb.y) * (1.0f / 128.0f) - mean * mean;
                float rstd = rsqrtf(var + 1e-5f);
                if (m >= M) continue;
                #pragma unroll
                for (int nf = 0; nf < 4; nf++) {
                    int n = n0 + nf * 16 + lrow;
                    float val = vals[mf][nf][r];
                    ((float*)outp)[(size_t)m * 128 + n] = val;
                    float o = (val - mean) * rstd * lg[n] + lb[n];
                    ((unsigned short*)hbout)[(size_t)m * 128 + n] = f2bf_bits(o);
                }
            }
        }
    }
}

// ---------- fused FFN: out += gelu(hb @ W1 + bf1) @ W2 + bf2 ----------
// Per block: 64 rows. Loop over 8 f-chunks (64 FFN dims each):
//   GEMM1 (K=128) -> gelu -> bf16 -> transpose via LDS midT -> GEMM2 (K=64) acc.
// midT [64 m][64 f] bf16, 128B rows of 8x16B chunks, XOR swizzle chunk^(m&7)
// (write and read sides both) -> ~2-way banks. W1/W2 chunks staged in the
// proven 64B-row gload_lds16 format. t never touches HBM (saves ~102 MB).
__global__ __launch_bounds__(256) void ffn_k(const bf16* __restrict__ hb,
                                             const bf16* __restrict__ w1,
                                             const bf16* __restrict__ w2,
                                             const float* __restrict__ bf1,
                                             const float* __restrict__ bf2,
                                             float* __restrict__ out, int M) {
    __shared__ __align__(16) char smem[57344];
    char* sA  = smem;              // [4 kc][64 r][64B]  hb tile
    char* sW1 = smem + 16384;      // [4 kc][64 r][64B]  W1 chunk (64 f-rows)
    char* sW2 = smem + 32768;      // [2 kc][128 r][64B] W2 chunk (128 n-rows x 64 f)
    char* sMT = smem + 49152;      // [64 m][128B]       gelu(mid) bf16, swizzled

    // XCD bijective remap (1-D grid)
    const int nwg = gridDim.x;
    const int orig = blockIdx.x;
    const int qq = nwg >> 3, rr = nwg & 7;
    const int xcd = orig & 7, jj = orig >> 3;
    const int by = ((xcd < rr) ? xcd * (qq + 1) : rr * (qq + 1) + (xcd - rr) * qq) + jj;

    const int lane = threadIdx.x & 63;
    const int wid  = threadIdx.x >> 6;
    const int wr = wid >> 1, wc = wid & 1;
    const int lrow = lane & 15, lk = lane >> 4;
    const int m0 = by * 64;
    const int srow = lane >> 2;
    const int schunk = (lane & 3) ^ ((srow >> 1) & 3);

    const char* Ab = (const char*)hb + (size_t)m0 * 256;   // 128k * 2B rows

    // stage A: 4 kchunks x (wave covers 16 rows each)
    #pragma unroll
    for (int ks = 0; ks < 4; ks++) {
        int rg = wid * 16;
        gload_lds16(Ab + (size_t)(rg + srow) * 256 + ks * 64 + schunk * 16,
                    sA + ks * 4096 + rg * 64);
    }

    auto stageW = [&](int fc) {
        const char* W1b = (const char*)w1 + (size_t)(fc * 64) * 256;   // rows fc*64.., 128k rows
        #pragma unroll
        for (int ks = 0; ks < 4; ks++) {
            int rg = wid * 16;
            gload_lds16(W1b + (size_t)(rg + srow) * 256 + ks * 64 + schunk * 16,
                        sW1 + ks * 4096 + rg * 64);
        }
        const char* W2b = (const char*)w2 + (size_t)(fc * 64) * 2;     // k-offset in 512k rows
        #pragma unroll
        for (int ks = 0; ks < 2; ks++) {
            #pragma unroll
            for (int it = 0; it < 2; it++) {
                int rg = wid * 32 + it * 16;
                gload_lds16(W2b + (size_t)(rg + srow) * 1024 + ks * 64 + schunk * 16,
                            sW2 + ks * 8192 + rg * 64);
            }
        }
    };

    f32x4 oacc[2][4];
    #pragma unroll
    for (int mf = 0; mf < 2; mf++)
        #pragma unroll
        for (int nf = 0; nf < 4; nf++) {
            f32x4 z = {0.f, 0.f, 0.f, 0.f};
            oacc[mf][nf] = z;
        }

    stageW(0);
    for (int fc = 0; fc < 8; fc++) {
        __syncthreads();                         // A + W(fc) staged
        // ---- GEMM1: mid[32m x 32f per wave], K=128 ----
        f32x4 macc[2][2];
        #pragma unroll
        for (int mf = 0; mf < 2; mf++)
            #pragma unroll
            for (int nf = 0; nf < 2; nf++) {
                f32x4 z = {0.f, 0.f, 0.f, 0.f};
                macc[mf][nf] = z;
            }
        #pragma unroll
        for (int ks = 0; ks < 4; ks++) {
            s16x8 a[2], bw[2];
            #pragma unroll
            for (int mf = 0; mf < 2; mf++) {
                int ra = wr * 32 + mf * 16 + lrow;
                a[mf] = *(const s16x8*)(sA + ks * 4096 + ra * 64 + ((lk ^ ((ra >> 1) & 3)) * 16));
            }
            #pragma unroll
            for (int nf = 0; nf < 2; nf++) {
                int rf = wc * 32 + nf * 16 + lrow;
                bw[nf] = *(const s16x8*)(sW1 + ks * 4096 + rf * 64 + ((lk ^ ((rf >> 1) & 3)) * 16));
            }
            #pragma unroll
            for (int mf = 0; mf < 2; mf++)
                #pragma unroll
                for (int nf = 0; nf < 2; nf++)
                    macc[mf][nf] = __builtin_amdgcn_mfma_f32_16x16x32_bf16(a[mf], bw[nf], macc[mf][nf], 0, 0, 0);
        }
        // ---- gelu -> bf16 -> midT (transposed, swizzled) ----
        #pragma unroll
        for (int mf = 0; mf < 2; mf++) {
            #pragma unroll
            for (int nf = 0; nf < 2; nf++) {
                int f = wc * 32 + nf * 16 + lrow;
                float bv = bf1[fc * 64 + f];
                #pragma unroll
                for (int r = 0; r < 4; r++) {
                    int m = wr * 32 + mf * 16 + lk * 4 + r;
                    float val = macc[mf][nf][r] + bv;
                    val = 0.5f * val * (1.0f + erff(val * 0.70710678118f));
                    int byte = m * 128 + (((f >> 3) ^ (m & 7)) * 16) + (f & 7) * 2;
                    *(unsigned short*)(sMT + byte) = f2bf_bits(val);
                }
            }
        }
        __syncthreads();                         // midT complete
        // ---- GEMM2: out[32m x 64n per wave], K=64 (2 ksteps) ----
        #pragma unroll
        for (int ks = 0; ks < 2; ks++) {
            s16x8 a2[2], b2[4];
            #pragma unroll
            for (int mf = 0; mf < 2; mf++) {
                int ra = wr * 32 + mf * 16 + lrow;
                int fch = ks * 4 + lk;            // f chunk index 0..7
                a2[mf] = *(const s16x8*)(sMT + ra * 128 + ((fch ^ (ra & 7)) * 16));
            }
            #pragma unroll
            for (int nf = 0; nf < 4; nf++) {
                int rb = wc * 64 + nf * 16 + lrow;
                b2[nf] = *(const s16x8*)(sW2 + ks * 8192 + rb * 64 + ((lk ^ ((rb >> 1) & 3)) * 16));
            }
            #pragma unroll
            for (int mf = 0; mf < 2; mf++)
                #pragma unroll
                for (int nf = 0; nf < 4; nf++)
                    oacc[mf][nf] = __builtin_amdgcn_mfma_f32_16x16x32_bf16(a2[mf], b2[nf], oacc[mf][nf], 0, 0, 0);
        }
        __syncthreads();                         // W/midT reads done -> safe restage
        if (fc + 1 < 8) stageW(fc + 1);
    }

    // ---- epilogue: out = oacc + bf2 + res(out), fp32 in-place ----
    #pragma unroll
    for (int mf = 0; mf < 2; mf++) {
        #pragma unroll
        for (int nf = 0; nf < 4; nf++) {
            int n = wc * 64 + nf * 16 + lrow;
            float bsv = bf2[n];
            #pragma unroll
            for (int r = 0; r < 4; r++) {
                int m = m0 + wr * 32 + mf * 16 + lk * 4 + r;
                if (m >= M) continue;
                float val = oacc[mf][nf][r] + bsv + out[(size_t)m * 128 + n];
                out[(size_t)m * 128 + n] = val;
            }
        }
    }
}

// ---------- node aggregation: one wave per dst node, CSR gather, no atomics ----------
// R5-measured-fast body: x8 unroll (16 gathers in flight), __expf, unscaled q.
__global__ __launch_bounds__(256) void node_agg_k(const bf16* __restrict__ q,
                                                  const bf16* __restrict__ k,
                                                  const bf16* __restrict__ v,
                                                  const int* __restrict__ off,
                                                  const int* __restrict__ deg,
                                                  const int* __restrict__ csr,
                                                  bf16* __restrict__ agg, int NN) {
    int node = blockIdx.x * 4 + (threadIdx.x >> 6);
    if (node >= NN) return;
    int lane = threadIdx.x & 63;
    float2 qf = bfpair(((const unsigned*)(q + (size_t)node * 128))[lane]);
    int start = off[node];
    int cnt = deg[node];
    float acc0 = 0.f, acc1 = 0.f, zsum = 0.f;
    if (cnt < 64) {
        int T = cnt + 1;                                  // + self-loop
        int s_vec = (lane < cnt) ? csr[start + lane] : node;
        for (int e0 = 0; e0 < T; e0 += 8) {
            unsigned ku[8], vu[8];
            #pragma unroll
            for (int j = 0; j < 8; j++) {
                if (e0 + j < T) {
                    int s = __shfl(s_vec, e0 + j);
                    ku[j] = ((const unsigned*)(k + (size_t)s * 128))[lane];
                    vu[j] = ((const unsigned*)(v + (size_t)s * 128))[lane];
                }
            }
            #pragma unroll
            for (int j = 0; j < 8; j++) {
                if (e0 + j < T) {
                    float2 kf = bfpair(ku[j]);
                    float dot = qf.x * kf.x + qf.y * kf.y;
                    dot += __shfl_xor(dot, 1);
                    dot += __shfl_xor(dot, 2);
                    dot += __shfl_xor(dot, 4);            // 8-lane (one head) reduce
                    float p = __expf(dot * 0.25f);
                    zsum += p;
                    float2 vf = bfpair(vu[j]);
                    acc0 += p * vf.x;
                    acc1 += p * vf.y;
                }
            }
        }
    } else {
        for (int e = 0; e <= cnt; e++) {
            int s = (e < cnt) ? csr[start + e] : node;
            float2 kf = bfpair(((const unsigned*)(k + (size_t)s * 128))[lane]);
            float dot = qf.x * kf.x + qf.y * kf.y;
            dot += __shfl_xor(dot, 1);
            dot += __shfl_xor(dot, 2);
            dot += __shfl_xor(dot, 4);
            float p = __expf(dot * 0.25f);
            zsum += p;
            float2 vf = bfpair(((const unsigned*)(v + (size_t)s * 128))[lane]);
            acc0 += p * vf.x;
            acc1 += p * vf.y;
        }
    }
    float2 o;
    if (cnt == 0) { o.x = 0.f; o.y = 0.f; }
    else { float inv = 1.0f / zsum; o.x = acc0 * inv; o.y = acc1 * inv; }
    unsigned pk = ((unsigned)f2bf_bits(o.y) << 16) | (unsigned)f2bf_bits(o.x);
    ((unsigned*)agg)[(size_t)node * 64 + lane] = pk;
}

// ---------- launch ----------
extern "C" void kernel_launch(void* const* d_in, const int* in_sizes, int n_in,
                              void* d_out, int out_size, void* d_ws, size_t ws_size,
                              hipStream_t stream) {
    const float* x  = (const float*)d_in[0];   // fp32, C-order [N,128]
    const void*  eiRaw = d_in[1];
    const float* Wq = (const float*)d_in[2];
    const float* bq = (const float*)d_in[3];
    const float* Wk = (const float*)d_in[4];
    const float* bk = (const float*)d_in[5];
    const float* Wv = (const float*)d_in[6];
    const float* bv = (const float*)d_in[7];
    const float* Wo = (const float*)d_in[8];
    const float* bo = (const float*)d_in[9];
    const float* g1 = (const float*)d_in[10];
    const float* b1 = (const float*)d_in[11];
    const float* g2 = (const float*)d_in[12];
    const float* b2 = (const float*)d_in[13];
    const float* W1 = (const float*)d_in[14];
    const float* bf1 = (const float*)d_in[15];
    const float* W2 = (const float*)d_in[16];
    const float* bf2 = (const float*)d_in[17];
    float* out = (float*)d_out;   // fp32 output; also holds x1

    const int N = in_sizes[0] / 128;
    const int E = in_sizes[1] / 2;
    const int gy = (N + 127) / 128;
    const int gy64 = (N + 63) / 64;
    const int Mp = gy * 128;      // padded row count for GEMM A-operands

    char* w = (char*)d_ws;
    size_t off_b = 0;
    auto alloc = [&](size_t bytes) -> void* {
        void* ptr = w + off_b;
        off_b = (off_b + bytes + 255) & ~(size_t)255;
        return ptr;
    };
    int*   deg    = (int*)alloc((size_t)N * 4);
    int*   offA   = (int*)alloc((size_t)N * 4);
    int*   cursor = (int*)alloc((size_t)N * 4);
    int*   bsum   = (int*)alloc(64 * 4);
    int*   ei32   = (int*)alloc((size_t)E * 2 * 4);
    int*   csr    = (int*)alloc((size_t)E * 4);
    bf16*  hb     = (bf16*)alloc((size_t)Mp * 128 * 2);   // LN1 out; reused for LN2 out
    bf16*  qkvb   = (bf16*)alloc((size_t)N * 3 * 128 * 2);
    bf16*  aggb   = (bf16*)alloc((size_t)Mp * 128 * 2);
    unsigned short* qkvH = (unsigned short*)alloc(49152 * 2);
    unsigned short* woH  = (unsigned short*)alloc(16384 * 2);
    unsigned short* w1H  = (unsigned short*)alloc(65536 * 2);
    unsigned short* w2H  = (unsigned short*)alloc(65536 * 2);
    float* bqkv = (float*)alloc(384 * 4);
    (void)ws_size; (void)n_in; (void)out_size;

    int nb = (N + SCAN_BLK - 1) / SCAN_BLK;
    int nzero = (N + 255) / 256;
    int lnb = (N + 3) / 4;

    // fused setup: weight prep | zero deg | canon edge_index | LN1
    setup_k<<<770 + nzero + 2000 + lnb, 256, 0, stream>>>(
        Wq, Wk, Wv, Wo, W1, W2, bq, bk, bv,
        qkvH, woH, w1H, w2H, bqkv,
        deg, (const unsigned*)eiRaw, ei32, x, g1, b1, hb, N, E * 2, nzero);
    // CSR build
    count_deg_k<<<(E + 255) / 256, 256, 0, stream>>>(ei32, deg, E);
    scan1_k<<<nb, 256, 0, stream>>>(deg, offA, bsum, N);
    scan3_k<<<(N + 255) / 256, 256, 0, stream>>>(offA, cursor, bsum, N, nb);
    scatter_k<<<(E + 255) / 256, 256, 0, stream>>>(ei32, cursor, csr, E);

    bf16* qb = qkvb;
    bf16* kb = qkvb + (size_t)N * 128;
    bf16* vb = qkvb + (size_t)N * 256;

    // 1. fused QKV GEMM: [q|k|v] = hb @ Wqkv + bqkv (bf16 out, split by n>>7)
    mgemm_k<0, true, 128, 128, false><<<dim3(3, gy), 256, 0, stream>>>(
        hb, (const bf16*)qkvH, bqkv, nullptr, qkvb,
        nullptr, nullptr, nullptr, (long long)N * 128, N, 128, 7);
    // 2. segment softmax + aggregation (bf16 out)
    node_agg_k<<<(N + 3) / 4, 256, 0, stream>>>(qb, kb, vb, offA, deg, csr, aggb, N);
    // 3. x1 = x + aggb @ Wo + bo -> out (fp32), fused LN2 -> hb (bf16)
    mgemm_k<2, false, 128, 64, true><<<dim3(1, gy64), 256, 0, stream>>>(
        aggb, (const bf16*)woH, bo, x, out,
        g2, b2, hb, 0, N, 128, 15);
    // 4. fused FFN: out = x1 + gelu(hb @ W1 + bf1) @ W2 + bf2 (t stays on-chip)
    ffn_k<<<gy64, 256, 0, stream>>>(hb, (const bf16*)w1H, (const bf16*)w2H,
                                    bf1, bf2, out, N);
}